// Round 5
// baseline (2657.489 us; speedup 1.0000x reference)
//
#include <hip/hip_runtime.h>
#include <math.h>

// ---- problem constants ----
constexpr int B_ = 64, L_ = 256, T_ = 32, E_ = 384, H_ = 6;
constexpr int DI_ = 768, DS_ = 16, DC_ = 4, DR_ = 24;
constexpr int HID_ = 1536, V_ = 97, ND_ = 12;
constexpr float EPS_ = 1e-5f;
constexpr int HD_ = 64;

typedef unsigned short ushort_t;
typedef __attribute__((ext_vector_type(8))) short  short8;
typedef __attribute__((ext_vector_type(4))) float  floatx4;
typedef __attribute__((ext_vector_type(8))) unsigned short ushort8v;

__device__ __forceinline__ float siluf(float x) { return x / (1.f + expf(-x)); }
__device__ __forceinline__ float softplusf(float x) {
    return fmaxf(x, 0.f) + log1pf(expf(-fabsf(x)));
}
__device__ __forceinline__ ushort_t f2bf(float f) {
    unsigned int u = __float_as_uint(f);
    u += 0x7fffu + ((u >> 16) & 1u);
    return (ushort_t)(u >> 16);
}
__device__ __forceinline__ float bf2f(ushort_t u) {
    return __uint_as_float(((unsigned int)u) << 16);
}
__device__ __forceinline__ void unpack2(unsigned int w, float& lo, float& hi) {
    lo = __uint_as_float(w << 16);
    hi = __uint_as_float(w & 0xffff0000u);
}
// async global->LDS, 16B/lane; dest = wave-uniform base + lane*16
__device__ __forceinline__ void gl_lds16(const ushort_t* g, ushort_t* l) {
    __builtin_amdgcn_global_load_lds(
        (const __attribute__((address_space(1))) unsigned int*)g,
        (__attribute__((address_space(3))) unsigned int*)l, 16, 0, 0);
}

// ---------------------------------------------------------------------------
// one-shot weight prep: bf16 conversions (+padding) and fp32 transposes.
// region order MUST match host pointer layout.
// ---------------------------------------------------------------------------
__global__ __launch_bounds__(256) void prep_kernel(
    const float* __restrict__ m_in_w, const float* __restrict__ m_xproj_w,
    const float* __restrict__ m_out_w,
    const float* __restrict__ wq, const float* __restrict__ wk,
    const float* __restrict__ wvv, const float* __restrict__ wo,
    const float* __restrict__ f1, const float* __restrict__ f2,
    const float* __restrict__ out_w,
    const float* __restrict__ m_dt_w, const float* __restrict__ m_Alog,
    ushort_t* __restrict__ w_in, ushort_t* __restrict__ w_xp,
    ushort_t* __restrict__ w_out_,
    ushort_t* __restrict__ w_q, ushort_t* __restrict__ w_k,
    ushort_t* __restrict__ w_v, ushort_t* __restrict__ w_o,
    ushort_t* __restrict__ w_f1, ushort_t* __restrict__ w_f2,
    ushort_t* __restrict__ w_lg,
    float* __restrict__ dtwT, float* __restrict__ negAT) {
    long i = (long)blockIdx.x * 256 + threadIdx.x;
    if (i < 7077888) { w_in[i] = f2bf(m_in_w[i]); return; } i -= 7077888;
    if (i < 589824) {
        int l = (int)(i / (64 * 768)); int rem = (int)(i % (64 * 768));
        int r = rem / 768, c = rem % 768;
        w_xp[i] = (r < 56) ? f2bf(m_xproj_w[((size_t)l * 56 + r) * 768 + c])
                           : (ushort_t)0;
        return; } i -= 589824;
    if (i < 3538944) { w_out_[i] = f2bf(m_out_w[i]); return; } i -= 3538944;
    if (i < 147456) { w_q[i] = f2bf(wq[i]); return; } i -= 147456;
    if (i < 147456) { w_k[i] = f2bf(wk[i]); return; } i -= 147456;
    if (i < 147456) { w_v[i] = f2bf(wvv[i]); return; } i -= 147456;
    if (i < 147456) { w_o[i] = f2bf(wo[i]); return; } i -= 147456;
    if (i < 589824) { w_f1[i] = f2bf(f1[i]); return; } i -= 589824;
    if (i < 589824) { w_f2[i] = f2bf(f2[i]); return; } i -= 589824;
    if (i < 49152) {
        int r = (int)(i / 384), c = (int)(i % 384);
        w_lg[i] = (r < 97) ? f2bf(out_w[r * 384 + c]) : (ushort_t)0;
        return; } i -= 49152;
    if (i < 221184) {  // dtwT [12][24][768] <- m_dt_w [12][768][24]
        int l = (int)(i / (24 * 768)); int rem = (int)(i % (24 * 768));
        int r = rem / 768, d = rem % 768;
        dtwT[i] = m_dt_w[((size_t)l * 768 + d) * 24 + r];
        return; } i -= 221184;
    if (i < 147456) {  // negAT [12][16][768] = -exp(Alog[12][768][16])
        int l = (int)(i / (16 * 768)); int rem = (int)(i % (16 * 768));
        int s = rem / 768, d = rem % 768;
        negAT[i] = -expf(m_Alog[((size_t)l * 768 + d) * 16 + s]);
        return; }
}
constexpr long PREP_TOTAL = 7077888L + 589824 + 3538944 + 4 * 147456
                          + 2 * 589824 + 49152 + 221184 + 147456;  // 13,393,920

// ---------------------------------------------------------------------------
// MEGAKERNEL. Blocks 0..63: full 12-layer mamba stack for batch b (1024 thr,
// 16 waves, 128 KB LDS; residual/hid/xm/dbl LDS-resident). Blocks 64..255:
// k/v projection (256x256 tiles over enc). No inter-block dependencies.
// ---------------------------------------------------------------------------
__global__ __launch_bounds__(1024) void mega_kernel(
    const float* __restrict__ qe, const float* __restrict__ pos,
    const ushort_t* __restrict__ w_in, const ushort_t* __restrict__ w_xp,
    const ushort_t* __restrict__ w_out,
    const float* __restrict__ convw, const float* __restrict__ convb,
    const float* __restrict__ dtwT, const float* __restrict__ dtb,
    const float* __restrict__ negAT, const float* __restrict__ Dpa,
    const float* __restrict__ normw, const float* __restrict__ rmsw,
    ushort_t* __restrict__ zbuf,
    ushort_t* __restrict__ g_hidden, float* __restrict__ g_res,
    const float* __restrict__ enc, const ushort_t* __restrict__ Wkv,
    const float* __restrict__ bk, const float* __restrict__ bv,
    ushort_t* __restrict__ kh, ushort_t* __restrict__ vh) {
    __shared__ union {
        struct {
            float res[32 * 384];      // 48 KB, persistent across layers
            ushort_t hid[32 * 384];   // 24 KB, swizzled
            ushort_t xm[32 * 768];    // 48 KB, swizzled (xm -> xc -> y in place)
            float dbl[32 * 64];       // 8 KB  (dt-in 0..23, B 24..39, C 40..55)
        } m;
        struct {
            ushort_t As[256 * 64];    // 32 KB
            ushort_t Bs[256 * 64];    // 32 KB
        } kv;
    } sm;

    const int tid = threadIdx.x;
    const int wv = tid >> 6, ln = tid & 63;
    const int lm = ln & 15, quad = ln >> 4;

    if (blockIdx.x >= 64) {
        // ================= KV projection path =================
        const int kb = blockIdx.x - 64;          // 0..191
        const int bm = (kb / 3) * 256;           // enc row base
        const int bnc = (kb % 3) * 256;          // combined col base (0..767)
        const int wr_ = wv >> 2, wc_ = wv & 3;   // 4x4 wave grid
        floatx4 acc[4][4] = {};
        const int arow = tid >> 2, aq = tid & 3;
        for (int k0 = 0; k0 < 384; k0 += 64) {
            {   // A stage: enc fp32 -> bf16, swizzled
                const float* ap = enc + (size_t)(bm + arow) * 384 + k0 + aq * 16;
                float4 v0 = ((const float4*)ap)[0];
                float4 v1 = ((const float4*)ap)[1];
                float4 v2 = ((const float4*)ap)[2];
                float4 v3 = ((const float4*)ap)[3];
                ushort8v o0, o1;
                o0[0] = f2bf(v0.x); o0[1] = f2bf(v0.y); o0[2] = f2bf(v0.z); o0[3] = f2bf(v0.w);
                o0[4] = f2bf(v1.x); o0[5] = f2bf(v1.y); o0[6] = f2bf(v1.z); o0[7] = f2bf(v1.w);
                o1[0] = f2bf(v2.x); o1[1] = f2bf(v2.y); o1[2] = f2bf(v2.z); o1[3] = f2bf(v2.w);
                o1[4] = f2bf(v3.x); o1[5] = f2bf(v3.y); o1[6] = f2bf(v3.z); o1[7] = f2bf(v3.w);
                *(ushort8v*)&sm.kv.As[arow * 64 + (((2 * aq) ^ (arow & 7)) << 3)] = o0;
                *(ushort8v*)&sm.kv.As[arow * 64 + (((2 * aq + 1) ^ (arow & 7)) << 3)] = o1;
            }
#pragma unroll
            for (int j = 0; j < 2; ++j) {   // B stage via global_load_lds
                int rowIdx = wv * 16 + j * 8 + (ln >> 3);
                int cg = (ln & 7) ^ (rowIdx & 7);
                gl_lds16(Wkv + (size_t)(bnc + rowIdx) * 384 + k0 + cg * 8,
                         &sm.kv.Bs[(wv * 16 + j * 8) * 64]);
            }
            __syncthreads();
#pragma unroll
            for (int ks = 0; ks < 2; ++ks) {
                short8 a[4], bb[4];
#pragma unroll
                for (int i = 0; i < 4; ++i) {
                    int rA = wr_ * 64 + i * 16 + lm;
                    a[i] = *(const short8*)&sm.kv.As[rA * 64 + (((ks * 4 + quad) ^ (rA & 7)) << 3)];
                }
#pragma unroll
                for (int i = 0; i < 4; ++i) {
                    int rB = wc_ * 64 + i * 16 + lm;
                    bb[i] = *(const short8*)&sm.kv.Bs[rB * 64 + (((ks * 4 + quad) ^ (rB & 7)) << 3)];
                }
#pragma unroll
                for (int i = 0; i < 4; ++i)
#pragma unroll
                    for (int j = 0; j < 4; ++j)
                        acc[i][j] = __builtin_amdgcn_mfma_f32_16x16x32_bf16(
                            a[i], bb[j], acc[i][j], 0, 0, 0);
            }
            __syncthreads();
        }
#pragma unroll
        for (int i = 0; i < 4; ++i)
#pragma unroll
            for (int j = 0; j < 4; ++j) {
                int gnc = bnc + wc_ * 64 + j * 16 + lm;
#pragma unroll
                for (int r = 0; r < 4; ++r) {
                    int m = bm + wr_ * 64 + i * 16 + quad * 4 + r;
                    float v = acc[i][j][r];
                    if (gnc < 384) kh[(size_t)m * 384 + gnc] = f2bf(v + bk[gnc]);
                    else vh[(size_t)m * 384 + (gnc - 384)] = f2bf(v + bv[gnc - 384]);
                }
            }
        return;
    }

    // ================= mamba path =================
    const int b = blockIdx.x;
    for (int i = tid; i < 32 * 384; i += 1024)
        sm.m.res[i] = qe[i] + pos[i];   // residual after layer-0's add
    __syncthreads();

    for (int l = 0; l < ND_; ++l) {
        const ushort_t* Wi = w_in + (size_t)l * 1536 * 384;
        const ushort_t* Wx = w_xp + (size_t)l * 64 * 768;
        const ushort_t* Wo = w_out + (size_t)l * 384 * 768;
        const float* nw = normw + l * 384;
        const float* cw = convw + l * 768 * 4;
        const float* cb = convb + l * 768;
        const float* dT = dtwT + l * 24 * 768;
        const float* db_ = dtb + l * 768;
        const float* nA_ = negAT + l * 16 * 768;
        const float* Dp_ = Dpa + l * 768;

        // --- phase A: rmsnorm RES -> HID (swizzled bf16); 2 rows/wave ---
#pragma unroll
        for (int rr = 0; rr < 2; ++rr) {
            int t = wv * 2 + rr;
            float x[6]; float s = 0.f;
#pragma unroll
            for (int j = 0; j < 6; ++j) {
                x[j] = sm.m.res[t * 384 + ln + j * 64];
                s += x[j] * x[j];
            }
#pragma unroll
            for (int off = 1; off < 64; off <<= 1) s += __shfl_xor(s, off);
            float sc = rsqrtf(s * (1.f / 384.f) + EPS_);
#pragma unroll
            for (int j = 0; j < 6; ++j) {
                int e = ln + j * 64;
                sm.m.hid[t * 384 + ((((e >> 3) ^ (t & 7)) << 3) | (e & 7))] =
                    f2bf(x[j] * sc * nw[e]);
            }
        }
        __syncthreads();

        // --- phase B: in_proj (wave w owns n in [96w,96w+96)) ---
        {
            floatx4 acc[2][6] = {};
            const int n0 = wv * 96;
            const int t0 = lm, t1 = 16 + lm;
            for (int q = 0; q < 12; ++q) {
                short8 a0 = *(const short8*)&sm.m.hid[t0 * 384 + (((q * 4 + quad) ^ (t0 & 7)) << 3)];
                short8 a1 = *(const short8*)&sm.m.hid[t1 * 384 + (((q * 4 + quad) ^ (t1 & 7)) << 3)];
#pragma unroll
                for (int nt = 0; nt < 6; ++nt) {
                    short8 bf = *(const short8*)(Wi + (size_t)(n0 + nt * 16 + lm) * 384 + q * 32 + quad * 8);
                    acc[0][nt] = __builtin_amdgcn_mfma_f32_16x16x32_bf16(a0, bf, acc[0][nt], 0, 0, 0);
                    acc[1][nt] = __builtin_amdgcn_mfma_f32_16x16x32_bf16(a1, bf, acc[1][nt], 0, 0, 0);
                }
            }
#pragma unroll
            for (int mt = 0; mt < 2; ++mt)
#pragma unroll
                for (int nt = 0; nt < 6; ++nt) {
                    int gn = n0 + nt * 16 + lm;
#pragma unroll
                    for (int r = 0; r < 4; ++r) {
                        int t = mt * 16 + quad * 4 + r;
                        float v = acc[mt][nt][r];
                        if (gn < 768)
                            sm.m.xm[t * 768 + ((((gn >> 3) ^ (t & 7)) << 3) | (gn & 7))] = f2bf(v);
                        else
                            zbuf[(size_t)(b * 32 + t) * 768 + (gn - 768)] = f2bf(siluf(v));
                    }
                }
        }
        __syncthreads();

        // --- phase C: depthwise conv + SiLU, in place (t descending) ---
        if (tid < 768) {
            int d = tid;
            float4 c4 = *(const float4*)(cw + d * 4);
            float cb0 = cb[d];
            int cc = d >> 3, jj = d & 7;
            for (int t = 31; t >= 0; --t) {
                float a = cb0;
#pragma unroll
                for (int k = 0; k < 4; ++k) {
                    int tt = t + k - 3;
                    if (tt >= 0) {
                        float xv = bf2f(sm.m.xm[tt * 768 + (((cc ^ (tt & 7)) << 3) | jj)]);
                        float wv_ = (k == 0) ? c4.x : (k == 1) ? c4.y : (k == 2) ? c4.z : c4.w;
                        a += wv_ * xv;
                    }
                }
                sm.m.xm[t * 768 + (((cc ^ (t & 7)) << 3) | jj)] = f2bf(siluf(a));
            }
        }
        __syncthreads();

        // --- phase D: xproj -> DBL (waves 0..7, one 16x16 tile each) ---
        if (wv < 8) {
            int mt = wv & 1, nt = wv >> 1;
            floatx4 acc = {};
            int t = mt * 16 + lm;
            int n = nt * 16 + lm;
#pragma unroll 4
            for (int q = 0; q < 24; ++q) {
                short8 a = *(const short8*)&sm.m.xm[t * 768 + (((q * 4 + quad) ^ (t & 7)) << 3)];
                short8 bf = *(const short8*)(Wx + (size_t)n * 768 + q * 32 + quad * 8);
                acc = __builtin_amdgcn_mfma_f32_16x16x32_bf16(a, bf, acc, 0, 0, 0);
            }
#pragma unroll
            for (int r = 0; r < 4; ++r) {
                int tt = mt * 16 + quad * 4 + r;
                sm.m.dbl[tt * 64 + nt * 16 + lm] = acc[r];
            }
        }
        __syncthreads();

        // --- phase E: dt-proj + selective scan + gate, y in place over xc ---
        if (tid < 768) {
            int d = tid;
            float wr[24];
#pragma unroll
            for (int r = 0; r < 24; ++r) wr[r] = dT[r * 768 + d];
            float dtb0 = db_[d];
            float nA[16];
#pragma unroll
            for (int s = 0; s < 16; ++s) nA[s] = nA_[s * 768 + d];
            float Dv = Dp_[d];
            float h[16] = {};
            int cc = d >> 3, jj = d & 7;
            for (int t = 0; t < 32; ++t) {
                float dtv = dtb0;
#pragma unroll
                for (int r = 0; r < 24; ++r) dtv += sm.m.dbl[t * 64 + r] * wr[r];
                dtv = softplusf(dtv);
                float xcv = bf2f(sm.m.xm[t * 768 + (((cc ^ (t & 7)) << 3) | jj)]);
                float a = 0.f;
#pragma unroll
                for (int s = 0; s < 16; ++s) {
                    h[s] = expf(dtv * nA[s]) * h[s] + dtv * sm.m.dbl[t * 64 + 24 + s] * xcv;
                    a += h[s] * sm.m.dbl[t * 64 + 40 + s];
                }
                float zv = bf2f(zbuf[(size_t)(b * 32 + t) * 768 + d]);
                sm.m.xm[t * 768 + (((cc ^ (t & 7)) << 3) | jj)] = f2bf((a + Dv * xcv) * zv);
            }
        }
        __syncthreads();

        // --- phase F: out_proj, RES += (wave w: mt=w&1, 3 n-tiles) ---
        {
            int mt = wv & 1, ntg = (wv >> 1) * 3;
            floatx4 acc[3] = {};
            int t = mt * 16 + lm;
#pragma unroll 4
            for (int q = 0; q < 24; ++q) {
                short8 a = *(const short8*)&sm.m.xm[t * 768 + (((q * 4 + quad) ^ (t & 7)) << 3)];
#pragma unroll
                for (int i = 0; i < 3; ++i) {
                    short8 bf = *(const short8*)(Wo + (size_t)((ntg + i) * 16 + lm) * 768 + q * 32 + quad * 8);
                    acc[i] = __builtin_amdgcn_mfma_f32_16x16x32_bf16(a, bf, acc[i], 0, 0, 0);
                }
            }
#pragma unroll
            for (int i = 0; i < 3; ++i)
#pragma unroll
                for (int r = 0; r < 4; ++r) {
                    int tt = mt * 16 + quad * 4 + r;
                    int n = (ntg + i) * 16 + lm;
                    sm.m.res[tt * 384 + n] += acc[i][r];
                }
        }
        __syncthreads();
    }

    // --- final rmsnorm -> g_hidden (plain layout); also flush residual ---
#pragma unroll
    for (int rr = 0; rr < 2; ++rr) {
        int t = wv * 2 + rr;
        float x[6]; float s = 0.f;
#pragma unroll
        for (int j = 0; j < 6; ++j) {
            x[j] = sm.m.res[t * 384 + ln + j * 64];
            s += x[j] * x[j];
        }
#pragma unroll
        for (int off = 1; off < 64; off <<= 1) s += __shfl_xor(s, off);
        float sc = rsqrtf(s * (1.f / 384.f) + EPS_);
#pragma unroll
        for (int j = 0; j < 6; ++j) {
            int e = ln + j * 64;
            size_t gi = (size_t)(b * 32 + t) * 384 + e;
            g_res[gi] = x[j];
            g_hidden[gi] = f2bf(x[j] * sc * rmsw[e]);
        }
    }
}

// ---------------------------------------------------------------------------
// 64x64-tile GEMM (round-3 proven). N padded to Nz, zero-filled.
// ---------------------------------------------------------------------------
template <int ACT, int OBF>
__global__ __launch_bounds__(256) void gemm_bf16(
    const ushort_t* __restrict__ A, int lda,
    const ushort_t* __restrict__ W,
    const float* __restrict__ bias,
    const float* __restrict__ addin,
    void* __restrict__ Cv,
    int M, int N, int K, int Nz, int ldc) {
    __shared__ ushort_t As[64 * 64];
    __shared__ ushort_t Bs[64 * 64];

    const int tid = threadIdx.x;
    const int wv = tid >> 6, ln = tid & 63;
    const int bm = blockIdx.x * 64, bn = blockIdx.y * 64;
    const int lm = ln & 15, quad = ln >> 4;
    const int wm = (wv & 1) * 32, wn = (wv >> 1) * 32;
    const int r8 = ln >> 3, c8 = ln & 7;

    floatx4 acc[2][2] = {};

    for (int k0 = 0; k0 < K; k0 += 64) {
#pragma unroll
        for (int j = 0; j < 2; ++j) {
            int row = wv * 16 + j * 8 + r8;
            int cg = c8 ^ (row & 7);
            gl_lds16(A + (size_t)(bm + row) * lda + k0 + cg * 8,
                     &As[(wv * 16 + j * 8) * 64]);
        }
#pragma unroll
        for (int j = 0; j < 2; ++j) {
            int row = wv * 16 + j * 8 + r8;
            int cg = c8 ^ (row & 7);
            gl_lds16(W + (size_t)(bn + row) * K + k0 + cg * 8,
                     &Bs[(wv * 16 + j * 8) * 64]);
        }
        __syncthreads();
#pragma unroll
        for (int ks2 = 0; ks2 < 2; ++ks2) {
            int pc = ((quad + ks2 * 4) ^ (lm & 7)) * 8;
            short8 a0 = *(const short8*)&As[(wm + lm) * 64 + pc];
            short8 a1 = *(const short8*)&As[(wm + 16 + lm) * 64 + pc];
            short8 b0 = *(const short8*)&Bs[(wn + lm) * 64 + pc];
            short8 b1 = *(const short8*)&Bs[(wn + 16 + lm) * 64 + pc];
            acc[0][0] = __builtin_amdgcn_mfma_f32_16x16x32_bf16(a0, b0, acc[0][0], 0, 0, 0);
            acc[0][1] = __builtin_amdgcn_mfma_f32_16x16x32_bf16(a0, b1, acc[0][1], 0, 0, 0);
            acc[1][0] = __builtin_amdgcn_mfma_f32_16x16x32_bf16(a1, b0, acc[1][0], 0, 0, 0);
            acc[1][1] = __builtin_amdgcn_mfma_f32_16x16x32_bf16(a1, b1, acc[1][1], 0, 0, 0);
        }
        __syncthreads();
    }

#pragma unroll
    for (int sm_ = 0; sm_ < 2; ++sm_) {
#pragma unroll
        for (int sn = 0; sn < 2; ++sn) {
            const int gn = bn + wn + sn * 16 + lm;
            if (gn >= Nz) continue;
#pragma unroll
            for (int r = 0; r < 4; ++r) {
                const int gm = bm + wm + sm_ * 16 + quad * 4 + r;
                float v;
                if (gn < N) {
                    v = acc[sm_][sn][r];
                    if (bias) v += bias[gn];
                    if (ACT == 1) v = fmaxf(v, 0.f);
                    if (addin) v += addin[(size_t)gm * ldc + gn];
                } else {
                    v = 0.f;
                }
                if (OBF)
                    ((ushort_t*)Cv)[(size_t)gm * ldc + gn] = f2bf(v);
                else
                    ((float*)Cv)[(size_t)gm * ldc + gn] = v;
            }
        }
    }
}

// wave-per-row layernorm, fp32 in -> bf16 out. grid=M/4.
__global__ __launch_bounds__(256) void layernorm_kernel(
    const float* __restrict__ xin, const float* __restrict__ w,
    const float* __restrict__ b, ushort_t* __restrict__ out) {
    const int row = blockIdx.x * 4 + (threadIdx.x >> 6);
    const int lane = threadIdx.x & 63;
    const long base = (long)row * E_;
    float x[6], s = 0.f, s2 = 0.f;
#pragma unroll
    for (int j = 0; j < 6; ++j) {
        x[j] = xin[base + lane + j * 64];
        s += x[j];
        s2 += x[j] * x[j];
    }
#pragma unroll
    for (int off = 1; off < 64; off <<= 1) {
        s += __shfl_xor(s, off);
        s2 += __shfl_xor(s2, off);
    }
    float mu = s / E_;
    float var = s2 / E_ - mu * mu;
    float sc = rsqrtf(var + EPS_);
#pragma unroll
    for (int j = 0; j < 6; ++j) {
        int c = lane + j * 64;
        out[base + c] = f2bf((x[j] - mu) * sc * w[c] + b[c]);
    }
}

// ---------------------------------------------------------------------------
// cross-attention: one block per (b,h). (unchanged, proven)
// ---------------------------------------------------------------------------
__global__ __launch_bounds__(256) void attn_kernel(
    const ushort_t* __restrict__ qh,
    const ushort_t* __restrict__ kh,
    const ushort_t* __restrict__ vh,
    ushort_t* __restrict__ ctx) {
    const int h = blockIdx.x % H_;
    const int b = blockIdx.x / H_;
    const int tid = threadIdx.x;

    __shared__ ushort_t Ks[L_ * HD_];
    __shared__ ushort_t Vs[L_ * HD_];
    __shared__ ushort_t Qs[T_ * HD_];
    __shared__ float Sc[T_ * L_];
    __shared__ float red8[T_][8];
    __shared__ float mx[T_], dn[T_];

    {
        int t = tid >> 3, c = tid & 7;
        *(uint4*)&Qs[t * 64 + c * 8] =
            *(const uint4*)(qh + (size_t)(b * T_ + t) * E_ + h * HD_ + c * 8);
    }
    {
        int s = tid;
        const ushort_t* kr = kh + (size_t)(b * L_ + s) * E_ + h * HD_;
        const ushort_t* vr = vh + (size_t)(b * L_ + s) * E_ + h * HD_;
#pragma unroll
        for (int c = 0; c < 8; ++c) {
            int cp = (c ^ (s & 7)) * 8;
            *(uint4*)&Ks[s * 64 + cp] = *(const uint4*)(kr + c * 8);
            *(uint4*)&Vs[s * 64 + cp] = *(const uint4*)(vr + c * 8);
        }
    }
    __syncthreads();

    {
        int s = tid;
        float kr[64];
#pragma unroll
        for (int c = 0; c < 8; ++c) {
            int cp = (c ^ (s & 7)) * 8;
            uint4 u = *(const uint4*)&Ks[s * 64 + cp];
            unpack2(u.x, kr[c * 8 + 0], kr[c * 8 + 1]);
            unpack2(u.y, kr[c * 8 + 2], kr[c * 8 + 3]);
            unpack2(u.z, kr[c * 8 + 4], kr[c * 8 + 5]);
            unpack2(u.w, kr[c * 8 + 6], kr[c * 8 + 7]);
        }
        for (int t = 0; t < T_; ++t) {
            float d = 0.f;
#pragma unroll
            for (int c = 0; c < 8; ++c) {
                uint4 qu = *(const uint4*)&Qs[t * 64 + c * 8];
                float q0, q1, q2, q3, q4, q5, q6, q7;
                unpack2(qu.x, q0, q1); unpack2(qu.y, q2, q3);
                unpack2(qu.z, q4, q5); unpack2(qu.w, q6, q7);
                d += q0 * kr[c * 8 + 0] + q1 * kr[c * 8 + 1] +
                     q2 * kr[c * 8 + 2] + q3 * kr[c * 8 + 3] +
                     q4 * kr[c * 8 + 4] + q5 * kr[c * 8 + 5] +
                     q6 * kr[c * 8 + 6] + q7 * kr[c * 8 + 7];
            }
            Sc[t * L_ + s] = d * 0.125f;
        }
    }
    __syncthreads();

    {
        int t = tid >> 3, j = tid & 7;
        float m = -1e30f;
        for (int s = j * 32; s < j * 32 + 32; ++s) m = fmaxf(m, Sc[t * L_ + s]);
        red8[t][j] = m;
    }
    __syncthreads();
    if (tid < T_) {
        float m = red8[tid][0];
#pragma unroll
        for (int j = 1; j < 8; ++j) m = fmaxf(m, red8[tid][j]);
        mx[tid] = m;
    }
    __syncthreads();
    {
        int t = tid >> 3, j = tid & 7;
        float m = mx[t], sum = 0.f;
        for (int s = j * 32; s < j * 32 + 32; ++s) {
            float e = expf(Sc[t * L_ + s] - m);
            Sc[t * L_ + s] = e;
            sum += e;
        }
        red8[t][j] = sum;
    }
    __syncthreads();
    if (tid < T_) {
        float s = 0.f;
#pragma unroll
        for (int j = 0; j < 8; ++j) s += red8[tid][j];
        dn[tid] = 1.f / s;
    }
    __syncthreads();

    {
        int t = tid >> 3, c = tid & 7;
        float o[8] = {};
        for (int si = 0; si < L_; ++si) {
            int s = (si + t * 33) & (L_ - 1);
            float p = Sc[t * L_ + s];
            int cp = (c ^ (s & 7)) * 8;
            uint4 u = *(const uint4*)&Vs[s * 64 + cp];
            float v0, v1, v2, v3, v4, v5, v6, v7;
            unpack2(u.x, v0, v1); unpack2(u.y, v2, v3);
            unpack2(u.z, v4, v5); unpack2(u.w, v6, v7);
            o[0] += p * v0; o[1] += p * v1; o[2] += p * v2; o[3] += p * v3;
            o[4] += p * v4; o[5] += p * v5; o[6] += p * v6; o[7] += p * v7;
        }
        float sc = dn[t];
        ushort8v pk;
#pragma unroll
        for (int j = 0; j < 8; ++j) pk[j] = f2bf(o[j] * sc);
        *(ushort8v*)(ctx + (size_t)(b * T_ + t) * E_ + h * HD_ + c * 8) = pk;
    }
}

// ---------------------------------------------------------------------------
static void g64(hipStream_t s, int act, int obf, const ushort_t* A, int lda,
                const ushort_t* W, const float* bias, const float* addin,
                void* C, int M, int N, int K, int Nz, int ldc) {
    dim3 g(M / 64, (Nz + 63) / 64), b(256);
    if (obf) {
        if (act == 1)
            gemm_bf16<1, 1><<<g, b, 0, s>>>(A, lda, W, bias, addin, C, M, N, K, Nz, ldc);
        else
            gemm_bf16<0, 1><<<g, b, 0, s>>>(A, lda, W, bias, addin, C, M, N, K, Nz, ldc);
    } else {
        gemm_bf16<0, 0><<<g, b, 0, s>>>(A, lda, W, bias, addin, C, M, N, K, Nz, ldc);
    }
}

extern "C" void kernel_launch(void* const* d_in, const int* in_sizes, int n_in,
                              void* d_out, int out_size, void* d_ws, size_t ws_size,
                              hipStream_t stream) {
    const float* enc      = (const float*)d_in[0];
    const float* qe       = (const float*)d_in[1];
    const float* pos      = (const float*)d_in[2];
    const float* m_norm_w = (const float*)d_in[3];
    const float* m_in_w   = (const float*)d_in[4];
    const float* m_conv_w = (const float*)d_in[5];
    const float* m_conv_b = (const float*)d_in[6];
    const float* m_xproj_w= (const float*)d_in[7];
    const float* m_dt_w   = (const float*)d_in[8];
    const float* m_dt_b   = (const float*)d_in[9];
    const float* m_Alog   = (const float*)d_in[10];
    const float* m_D      = (const float*)d_in[11];
    const float* m_out_w  = (const float*)d_in[12];
    const float* rms_w    = (const float*)d_in[13];
    const float* wq = (const float*)d_in[14];
    const float* bq = (const float*)d_in[15];
    const float* wk = (const float*)d_in[16];
    const float* bk = (const float*)d_in[17];
    const float* wv = (const float*)d_in[18];
    const float* bv = (const float*)d_in[19];
    const float* wo = (const float*)d_in[20];
    const float* bo = (const float*)d_in[21];
    const float* ln1_w = (const float*)d_in[22];
    const float* ln1_b = (const float*)d_in[23];
    const float* ffn_w1 = (const float*)d_in[24];
    const float* ffn_b1 = (const float*)d_in[25];
    const float* ffn_w2 = (const float*)d_in[26];
    const float* ffn_b2 = (const float*)d_in[27];
    const float* ln2_w = (const float*)d_in[28];
    const float* ln2_b = (const float*)d_in[29];
    const float* out_w = (const float*)d_in[30];
    const float* out_b = (const float*)d_in[31];

    // ---- workspace layout ----
    float* residual = (float*)d_ws;                  // 786,432 f
    float* dtwT = residual + 786432;                 // 221,184 f
    float* negAT = dtwT + 221184;                    // 147,456 f
    ushort_t* U = (ushort_t*)(negAT + 147456);
    ushort_t* hidden = U;                            // 786,432
    ushort_t* qh  = hidden + 786432;                 // 786,432
    ushort_t* ctx = qh + 786432;                     // 786,432
    ushort_t* kh  = ctx + 786432;                    // 6,291,456
    ushort_t* vh  = kh + 6291456;                    // 6,291,456
    ushort_t* ffnb = vh + 6291456;                   // 3,145,728
    ushort_t* zbuf = ffnb + 3145728;                 // 1,572,864
    ushort_t* w_in  = zbuf + 1572864;                // 7,077,888
    ushort_t* w_xp  = w_in + 7077888;                //   589,824
    ushort_t* w_out = w_xp + 589824;                 // 3,538,944
    ushort_t* w_q   = w_out + 3538944;               //   147,456
    ushort_t* w_k   = w_q + 147456;                  //   147,456
    ushort_t* w_v   = w_k + 147456;                  //   147,456 (adjacent to w_k!)
    ushort_t* w_o   = w_v + 147456;                  //   147,456
    ushort_t* w_f1  = w_o + 147456;                  //   589,824
    ushort_t* w_f2  = w_f1 + 589824;                 //   589,824
    ushort_t* w_lg  = w_f2 + 589824;                 //    49,152

    const int M = B_ * T_;  // 2048

    // 1) weight prep (single launch)
    prep_kernel<<<(int)((PREP_TOTAL + 255) / 256), 256, 0, stream>>>(
        m_in_w, m_xproj_w, m_out_w, wq, wk, wv, wo, ffn_w1, ffn_w2, out_w,
        m_dt_w, m_Alog,
        w_in, w_xp, w_out, w_q, w_k, w_v, w_o, w_f1, w_f2, w_lg, dtwT, negAT);

    // 2) megakernel: 64 mamba blocks + 192 kv blocks
    mega_kernel<<<256, 1024, 0, stream>>>(
        qe, pos, w_in, w_xp, w_out, m_conv_w, m_conv_b, dtwT, m_dt_b,
        negAT, m_D, m_norm_w, rms_w, zbuf, hidden, residual,
        enc, w_k, bk, bv, kh, vh);

    // 3) tail
    g64(stream, 0, 1, hidden, 384, w_q, bq, nullptr, qh, M, 384, 384, 384, 384);
    attn_kernel<<<B_ * H_, 256, 0, stream>>>(qh, kh, vh, ctx);
    g64(stream, 0, 0, ctx, 384, w_o, bo, residual, residual, M, 384, 384, 384, 384);
    layernorm_kernel<<<M / 4, 256, 0, stream>>>(residual, ln1_w, ln1_b, hidden);
    g64(stream, 1, 1, hidden, 384, w_f1, ffn_b1, nullptr, ffnb, M, 1536, 384, 1536, 1536);
    g64(stream, 0, 0, ffnb, 1536, w_f2, ffn_b2, residual, residual, M, 384, 1536, 384, 384);
    layernorm_kernel<<<M / 4, 256, 0, stream>>>(residual, ln2_w, ln2_b, hidden);
    g64(stream, 0, 0, hidden, 384, w_lg, out_b, nullptr, (float*)d_out, M, 97, 384, 97, 97);
}

// Round 6
// 1972.150 us; speedup vs baseline: 1.3475x; 1.3475x over previous
//
#include <hip/hip_runtime.h>
#include <math.h>

// ---- problem constants ----
constexpr int B_ = 64, L_ = 256, T_ = 32, E_ = 384, H_ = 6;
constexpr int DI_ = 768, DS_ = 16, DC_ = 4, DR_ = 24;
constexpr int HID_ = 1536, V_ = 97, ND_ = 12;
constexpr float EPS_ = 1e-5f;
constexpr int HD_ = 64;

typedef unsigned short ushort_t;
typedef __attribute__((ext_vector_type(8))) short  short8;
typedef __attribute__((ext_vector_type(4))) float  floatx4;
typedef __attribute__((ext_vector_type(4))) unsigned short ushort4v;
typedef __attribute__((ext_vector_type(8))) unsigned short ushort8v;

__device__ __forceinline__ float siluf(float x) { return x / (1.f + expf(-x)); }
__device__ __forceinline__ float softplusf(float x) {
    return fmaxf(x, 0.f) + log1pf(expf(-fabsf(x)));
}
__device__ __forceinline__ ushort_t f2bf(float f) {
    unsigned int u = __float_as_uint(f);
    u += 0x7fffu + ((u >> 16) & 1u);
    return (ushort_t)(u >> 16);
}
__device__ __forceinline__ float bf2f(ushort_t u) {
    return __uint_as_float(((unsigned int)u) << 16);
}
__device__ __forceinline__ void unpack2(unsigned int w, float& lo, float& hi) {
    lo = __uint_as_float(w << 16);
    hi = __uint_as_float(w & 0xffff0000u);
}
// async global->LDS, 16B/lane; dest = wave-uniform base + lane*16
__device__ __forceinline__ void gl_lds16(const ushort_t* g, ushort_t* l) {
    __builtin_amdgcn_global_load_lds(
        (const __attribute__((address_space(1))) unsigned int*)g,
        (__attribute__((address_space(3))) unsigned int*)l, 16, 0, 0);
}

// ---------------------------------------------------------------------------
// one-shot prep: weight bf16 conversions (+pad), transposes, enc cvt, kv bias
// ---------------------------------------------------------------------------
__global__ __launch_bounds__(256) void prep_kernel(
    const float* __restrict__ m_in_w, const float* __restrict__ m_xproj_w,
    const float* __restrict__ m_out_w,
    const float* __restrict__ wq, const float* __restrict__ wk,
    const float* __restrict__ wvv, const float* __restrict__ wo,
    const float* __restrict__ f1, const float* __restrict__ f2,
    const float* __restrict__ out_w,
    const float* __restrict__ m_dt_w, const float* __restrict__ m_Alog,
    const float* __restrict__ enc,
    const float* __restrict__ bk, const float* __restrict__ bv,
    ushort_t* __restrict__ w_in, ushort_t* __restrict__ w_xp,
    ushort_t* __restrict__ w_out_,
    ushort_t* __restrict__ w_q, ushort_t* __restrict__ w_k,
    ushort_t* __restrict__ w_v, ushort_t* __restrict__ w_o,
    ushort_t* __restrict__ w_f1, ushort_t* __restrict__ w_f2,
    ushort_t* __restrict__ w_lg,
    float* __restrict__ dtwT, float* __restrict__ negAT,
    ushort_t* __restrict__ enc_bf, float* __restrict__ kvb) {
    long i = (long)blockIdx.x * 256 + threadIdx.x;
    if (i < 7077888) { w_in[i] = f2bf(m_in_w[i]); return; } i -= 7077888;
    if (i < 589824) {
        int l = (int)(i / (64 * 768)); int rem = (int)(i % (64 * 768));
        int r = rem / 768, c = rem % 768;
        w_xp[i] = (r < 56) ? f2bf(m_xproj_w[((size_t)l * 56 + r) * 768 + c])
                           : (ushort_t)0;
        return; } i -= 589824;
    if (i < 3538944) { w_out_[i] = f2bf(m_out_w[i]); return; } i -= 3538944;
    if (i < 147456) { w_q[i] = f2bf(wq[i]); return; } i -= 147456;
    if (i < 147456) { w_k[i] = f2bf(wk[i]); return; } i -= 147456;
    if (i < 147456) { w_v[i] = f2bf(wvv[i]); return; } i -= 147456;
    if (i < 147456) { w_o[i] = f2bf(wo[i]); return; } i -= 147456;
    if (i < 589824) { w_f1[i] = f2bf(f1[i]); return; } i -= 589824;
    if (i < 589824) { w_f2[i] = f2bf(f2[i]); return; } i -= 589824;
    if (i < 49152) {
        int r = (int)(i / 384), c = (int)(i % 384);
        w_lg[i] = (r < 97) ? f2bf(out_w[r * 384 + c]) : (ushort_t)0;
        return; } i -= 49152;
    if (i < 221184) {  // dtwT [12][24][768] <- m_dt_w [12][768][24]
        int l = (int)(i / (24 * 768)); int rem = (int)(i % (24 * 768));
        int r = rem / 768, d = rem % 768;
        dtwT[i] = m_dt_w[((size_t)l * 768 + d) * 24 + r];
        return; } i -= 221184;
    if (i < 147456) {  // negAT [12][16][768] = -exp(Alog)
        int l = (int)(i / (16 * 768)); int rem = (int)(i % (16 * 768));
        int s = rem / 768, d = rem % 768;
        negAT[i] = -expf(m_Alog[((size_t)l * 768 + d) * 16 + s]);
        return; } i -= 147456;
    if (i < 6291456) { enc_bf[i] = f2bf(enc[i]); return; } i -= 6291456;
    if (i < 768) { kvb[i] = (i < 384) ? bk[i] : bv[i - 384]; return; }
}
constexpr long PREP_TOTAL = 7077888L + 589824 + 3538944 + 4 * 147456
    + 2 * 589824 + 49152 + 221184 + 147456 + 6291456 + 768;

// ---------------------------------------------------------------------------
// init: res = qe + pos (broadcast over B)
// ---------------------------------------------------------------------------
__global__ void init_kernel(const float* __restrict__ qe,
                            const float* __restrict__ pos,
                            float* __restrict__ res) {
    long idx = (long)blockIdx.x * 256 + threadIdx.x;
    if (idx >= (long)B_ * T_ * E_) return;
    int te = (int)(idx % ((long)T_ * E_));
    res[idx] = qe[te] + pos[te];
}

// ---------------------------------------------------------------------------
// Norm-fused GEMM, K=384 fixed. A = norm(res row) computed in prologue.
// NORM: 0 rmsnorm (nw), 1 layernorm (nw, nb).
// EPI: 0 plain(+bias), 1 relu(+bias), 3 z-silu (silu for gn>=768, no bias).
// OBF: 1 bf16 out, 0 fp32 out. Writes only gn < N.
// grid (M/64, ceil(N/64)) x 256 threads. W is [Npad][384] bf16.
// ---------------------------------------------------------------------------
template <int NORM, int EPI, int OBF>
__global__ __launch_bounds__(256) void fused_gemm(
    const float* __restrict__ res,
    const float* __restrict__ nw, const float* __restrict__ nb,
    const ushort_t* __restrict__ W,
    const float* __restrict__ bias,
    void* __restrict__ Cv, int N, int ldc) {
    __shared__ ushort_t Apan[64 * 384];  // 48 KB
    __shared__ ushort_t Bs[64 * 64];     // 8 KB

    const int tid = threadIdx.x;
    const int wv = tid >> 6, ln = tid & 63;
    const int bm = blockIdx.x * 64, bn = blockIdx.y * 64;
    const int lm = ln & 15, quad = ln >> 4;
    const int wm = (wv & 1) * 32, wn = (wv >> 1) * 32;
    const int r8 = ln >> 3, c8 = ln & 7;

    // ---- prologue: per-row norm + bf16 A panel (4 threads/row) ----
    {
        const int r = tid >> 2, cq = tid & 3;
        const float* rp = res + (size_t)(bm + r) * 384 + cq * 96;
        float s = 0.f, s2 = 0.f;
#pragma unroll 4
        for (int i = 0; i < 24; ++i) {
            float4 v = ((const float4*)rp)[i];
            if (NORM == 1) s += v.x + v.y + v.z + v.w;
            s2 += v.x * v.x + v.y * v.y + v.z * v.z + v.w * v.w;
        }
        if (NORM == 1) { s += __shfl_xor(s, 1); s += __shfl_xor(s, 2); }
        s2 += __shfl_xor(s2, 1); s2 += __shfl_xor(s2, 2);
        float mu = (NORM == 1) ? s * (1.f / 384.f) : 0.f;
        float var = (NORM == 1) ? s2 * (1.f / 384.f) - mu * mu
                                : s2 * (1.f / 384.f);
        float sc = rsqrtf(var + EPS_);
#pragma unroll 4
        for (int i = 0; i < 24; ++i) {
            float4 v = ((const float4*)rp)[i];
            int col = cq * 96 + i * 4;
            float o0 = (v.x - mu) * sc * nw[col + 0];
            float o1 = (v.y - mu) * sc * nw[col + 1];
            float o2 = (v.z - mu) * sc * nw[col + 2];
            float o3 = (v.w - mu) * sc * nw[col + 3];
            if (NORM == 1) {
                o0 += nb[col + 0]; o1 += nb[col + 1];
                o2 += nb[col + 2]; o3 += nb[col + 3];
            }
            ushort4v pk;
            pk[0] = f2bf(o0); pk[1] = f2bf(o1); pk[2] = f2bf(o2); pk[3] = f2bf(o3);
            int chunk = col >> 3;
            *(ushort4v*)&Apan[r * 384 + (((chunk ^ (r & 7)) << 3) | (col & 7))] = pk;
        }
    }

    floatx4 acc[2][2] = {};

    for (int k0 = 0; k0 < 384; k0 += 64) {
#pragma unroll
        for (int j = 0; j < 2; ++j) {
            int row = wv * 16 + j * 8 + r8;
            int cg = c8 ^ (row & 7);
            gl_lds16(W + (size_t)(bn + row) * 384 + k0 + cg * 8,
                     &Bs[(wv * 16 + j * 8) * 64]);
        }
        __syncthreads();   // also covers Apan writes on first iteration
#pragma unroll
        for (int ks2 = 0; ks2 < 2; ++ks2) {
            int sub = ks2 * 4 + quad;          // 0..7
            int ra0 = wm + lm, ra1 = wm + 16 + lm;
            int ca0 = ((k0 >> 3) + (sub ^ (ra0 & 7))) << 3;
            int ca1 = ((k0 >> 3) + (sub ^ (ra1 & 7))) << 3;
            short8 a0 = *(const short8*)&Apan[ra0 * 384 + ca0];
            short8 a1 = *(const short8*)&Apan[ra1 * 384 + ca1];
            int pc = (sub ^ (lm & 7)) * 8;
            short8 b0 = *(const short8*)&Bs[(wn + lm) * 64 + pc];
            short8 b1 = *(const short8*)&Bs[(wn + 16 + lm) * 64 + pc];
            acc[0][0] = __builtin_amdgcn_mfma_f32_16x16x32_bf16(a0, b0, acc[0][0], 0, 0, 0);
            acc[0][1] = __builtin_amdgcn_mfma_f32_16x16x32_bf16(a0, b1, acc[0][1], 0, 0, 0);
            acc[1][0] = __builtin_amdgcn_mfma_f32_16x16x32_bf16(a1, b0, acc[1][0], 0, 0, 0);
            acc[1][1] = __builtin_amdgcn_mfma_f32_16x16x32_bf16(a1, b1, acc[1][1], 0, 0, 0);
        }
        __syncthreads();
    }

    // C/D layout: col = lane&15, row = quad*4 + reg  [m89-verified]
#pragma unroll
    for (int sm_ = 0; sm_ < 2; ++sm_) {
#pragma unroll
        for (int sn = 0; sn < 2; ++sn) {
            const int gn = bn + wn + sn * 16 + lm;
            if (gn >= N) continue;
#pragma unroll
            for (int r = 0; r < 4; ++r) {
                const int gm = bm + wm + sm_ * 16 + quad * 4 + r;
                float v = acc[sm_][sn][r];
                if (bias) v += bias[gn];
                if (EPI == 1) v = fmaxf(v, 0.f);
                if (EPI == 3 && gn >= 768) v = siluf(v);
                if (OBF)
                    ((ushort_t*)Cv)[(size_t)gm * ldc + gn] = f2bf(v);
                else
                    ((float*)Cv)[(size_t)gm * ldc + gn] = v;
            }
        }
    }
}

// ---------------------------------------------------------------------------
// plain 64x64 bf16 GEMM (round-3 proven). A bf16 [M][lda].
// ---------------------------------------------------------------------------
template <int OBF>
__global__ __launch_bounds__(256) void gemm_bf16(
    const ushort_t* __restrict__ A, int lda,
    const ushort_t* __restrict__ W,
    const float* __restrict__ bias,
    const float* __restrict__ addin,
    void* __restrict__ Cv,
    int M, int N, int K, int ldc) {
    __shared__ ushort_t As[64 * 64];
    __shared__ ushort_t Bs[64 * 64];

    const int tid = threadIdx.x;
    const int wv = tid >> 6, ln = tid & 63;
    const int bm = blockIdx.x * 64, bn = blockIdx.y * 64;
    const int lm = ln & 15, quad = ln >> 4;
    const int wm = (wv & 1) * 32, wn = (wv >> 1) * 32;
    const int r8 = ln >> 3, c8 = ln & 7;

    floatx4 acc[2][2] = {};

    for (int k0 = 0; k0 < K; k0 += 64) {
#pragma unroll
        for (int j = 0; j < 2; ++j) {
            int row = wv * 16 + j * 8 + r8;
            int cg = c8 ^ (row & 7);
            gl_lds16(A + (size_t)(bm + row) * lda + k0 + cg * 8,
                     &As[(wv * 16 + j * 8) * 64]);
        }
#pragma unroll
        for (int j = 0; j < 2; ++j) {
            int row = wv * 16 + j * 8 + r8;
            int cg = c8 ^ (row & 7);
            gl_lds16(W + (size_t)(bn + row) * K + k0 + cg * 8,
                     &Bs[(wv * 16 + j * 8) * 64]);
        }
        __syncthreads();
#pragma unroll
        for (int ks2 = 0; ks2 < 2; ++ks2) {
            int pc = ((quad + ks2 * 4) ^ (lm & 7)) * 8;
            short8 a0 = *(const short8*)&As[(wm + lm) * 64 + pc];
            short8 a1 = *(const short8*)&As[(wm + 16 + lm) * 64 + pc];
            short8 b0 = *(const short8*)&Bs[(wn + lm) * 64 + pc];
            short8 b1 = *(const short8*)&Bs[(wn + 16 + lm) * 64 + pc];
            acc[0][0] = __builtin_amdgcn_mfma_f32_16x16x32_bf16(a0, b0, acc[0][0], 0, 0, 0);
            acc[0][1] = __builtin_amdgcn_mfma_f32_16x16x32_bf16(a0, b1, acc[0][1], 0, 0, 0);
            acc[1][0] = __builtin_amdgcn_mfma_f32_16x16x32_bf16(a1, b0, acc[1][0], 0, 0, 0);
            acc[1][1] = __builtin_amdgcn_mfma_f32_16x16x32_bf16(a1, b1, acc[1][1], 0, 0, 0);
        }
        __syncthreads();
    }

#pragma unroll
    for (int sm_ = 0; sm_ < 2; ++sm_) {
#pragma unroll
        for (int sn = 0; sn < 2; ++sn) {
            const int gn = bn + wn + sn * 16 + lm;
            if (gn >= N) continue;
#pragma unroll
            for (int r = 0; r < 4; ++r) {
                const int gm = bm + wm + sm_ * 16 + quad * 4 + r;
                float v = acc[sm_][sn][r];
                if (bias) v += bias[gn];
                if (addin) v += addin[(size_t)gm * ldc + gn];
                if (OBF)
                    ((ushort_t*)Cv)[(size_t)gm * ldc + gn] = f2bf(v);
                else
                    ((float*)Cv)[(size_t)gm * ldc + gn] = v;
            }
        }
    }
}

// ---------------------------------------------------------------------------
// conv + xproj + dt-proj + selective scan + gate. one block per b, 768 thr.
// ---------------------------------------------------------------------------
__global__ __launch_bounds__(768) void convscan_kernel(
    const ushort_t* __restrict__ xz,     // B*T*1536 (silu(z) at +768)
    const float* __restrict__ cw, const float* __restrict__ cb,
    const ushort_t* __restrict__ Wx,     // 64 x 768 bf16 (layer slice)
    const float* __restrict__ dT, const float* __restrict__ db_,
    const float* __restrict__ nA_, const float* __restrict__ Dp_,
    ushort_t* __restrict__ yb) {
    __shared__ ushort_t xm[32 * 768];    // 48 KB, swizzled
    __shared__ float dbl[32 * 64];       // 8 KB

    const int tid = threadIdx.x;
    const int wv = tid >> 6, ln = tid & 63;
    const int lm = ln & 15, quad = ln >> 4;
    const int b = blockIdx.x;

    // stage xm (32x768) swizzled
    for (int ci = tid; ci < 3072; ci += 768) {
        int t = ci / 96, c8 = ci % 96;
        ushort8v v = *(const ushort8v*)(xz + (size_t)(b * 32 + t) * 1536 + c8 * 8);
        *(ushort8v*)&xm[t * 768 + ((c8 ^ (t & 7)) << 3)] = v;
    }
    __syncthreads();

    // depthwise conv + SiLU, in place, t descending
    {
        int d = tid;
        float4 c4 = *(const float4*)(cw + d * 4);
        float cb0 = cb[d];
        int cc = d >> 3, jj = d & 7;
        for (int t = 31; t >= 0; --t) {
            float a = cb0;
#pragma unroll
            for (int k = 0; k < 4; ++k) {
                int tt = t + k - 3;
                if (tt >= 0) {
                    float xv = bf2f(xm[tt * 768 + (((cc ^ (tt & 7)) << 3) | jj)]);
                    float wv_ = (k == 0) ? c4.x : (k == 1) ? c4.y : (k == 2) ? c4.z : c4.w;
                    a += wv_ * xv;
                }
            }
            xm[t * 768 + (((cc ^ (t & 7)) << 3) | jj)] = f2bf(siluf(a));
        }
    }
    __syncthreads();

    // xproj -> dbl (waves 0..7, one 16x16 tile each)
    if (wv < 8) {
        int mt = wv & 1, nt = wv >> 1;
        floatx4 acc = {};
        int t = mt * 16 + lm;
        int n = nt * 16 + lm;
#pragma unroll 4
        for (int q = 0; q < 24; ++q) {
            short8 a = *(const short8*)&xm[t * 768 + (((q * 4 + quad) ^ (t & 7)) << 3)];
            short8 bf = *(const short8*)(Wx + (size_t)n * 768 + q * 32 + quad * 8);
            acc = __builtin_amdgcn_mfma_f32_16x16x32_bf16(a, bf, acc, 0, 0, 0);
        }
#pragma unroll
        for (int r = 0; r < 4; ++r)
            dbl[(mt * 16 + quad * 4 + r) * 64 + nt * 16 + lm] = acc[r];
    }
    __syncthreads();

    // dt-proj + scan + gate -> yb
    {
        int d = tid;
        float wr[24];
#pragma unroll
        for (int r = 0; r < 24; ++r) wr[r] = dT[r * 768 + d];
        float dtb0 = db_[d];
        float nA[16];
#pragma unroll
        for (int s = 0; s < 16; ++s) nA[s] = nA_[s * 768 + d];
        float Dv = Dp_[d];
        float h[16] = {};
        int cc = d >> 3, jj = d & 7;
        for (int t = 0; t < 32; ++t) {
            float dtv = dtb0;
#pragma unroll
            for (int r = 0; r < 24; ++r) dtv += dbl[t * 64 + r] * wr[r];
            dtv = softplusf(dtv);
            float xcv = bf2f(xm[t * 768 + (((cc ^ (t & 7)) << 3) | jj)]);
            float a = 0.f;
#pragma unroll
            for (int s = 0; s < 16; ++s) {
                h[s] = expf(dtv * nA[s]) * h[s] + dtv * dbl[t * 64 + 24 + s] * xcv;
                a += h[s] * dbl[t * 64 + 40 + s];
            }
            float zv = bf2f(xz[(size_t)(b * 32 + t) * 1536 + 768 + d]);
            yb[(size_t)(b * 32 + t) * 768 + d] = f2bf((a + Dv * xcv) * zv);
        }
    }
}

// ---------------------------------------------------------------------------
// cross-attention, one block per (b,h). khv combined layout [b*L][768].
// ---------------------------------------------------------------------------
__global__ __launch_bounds__(256) void attn_kernel(
    const ushort_t* __restrict__ qh,
    const ushort_t* __restrict__ khv,
    ushort_t* __restrict__ ctx) {
    const int h = blockIdx.x % H_;
    const int b = blockIdx.x / H_;
    const int tid = threadIdx.x;

    __shared__ ushort_t Ks[L_ * HD_];
    __shared__ ushort_t Vs[L_ * HD_];
    __shared__ ushort_t Qs[T_ * HD_];
    __shared__ float Sc[T_ * L_];
    __shared__ float red8[T_][8];
    __shared__ float mx[T_], dn[T_];

    {
        int t = tid >> 3, c = tid & 7;
        *(uint4*)&Qs[t * 64 + c * 8] =
            *(const uint4*)(qh + (size_t)(b * T_ + t) * E_ + h * HD_ + c * 8);
    }
    {
        int s = tid;
        const ushort_t* kr = khv + (size_t)(b * L_ + s) * 768 + h * HD_;
        const ushort_t* vr = kr + 384;
#pragma unroll
        for (int c = 0; c < 8; ++c) {
            int cp = (c ^ (s & 7)) * 8;
            *(uint4*)&Ks[s * 64 + cp] = *(const uint4*)(kr + c * 8);
            *(uint4*)&Vs[s * 64 + cp] = *(const uint4*)(vr + c * 8);
        }
    }
    __syncthreads();

    {
        int s = tid;
        float kr[64];
#pragma unroll
        for (int c = 0; c < 8; ++c) {
            int cp = (c ^ (s & 7)) * 8;
            uint4 u = *(const uint4*)&Ks[s * 64 + cp];
            unpack2(u.x, kr[c * 8 + 0], kr[c * 8 + 1]);
            unpack2(u.y, kr[c * 8 + 2], kr[c * 8 + 3]);
            unpack2(u.z, kr[c * 8 + 4], kr[c * 8 + 5]);
            unpack2(u.w, kr[c * 8 + 6], kr[c * 8 + 7]);
        }
        for (int t = 0; t < T_; ++t) {
            float d = 0.f;
#pragma unroll
            for (int c = 0; c < 8; ++c) {
                uint4 qu = *(const uint4*)&Qs[t * 64 + c * 8];
                float q0, q1, q2, q3, q4, q5, q6, q7;
                unpack2(qu.x, q0, q1); unpack2(qu.y, q2, q3);
                unpack2(qu.z, q4, q5); unpack2(qu.w, q6, q7);
                d += q0 * kr[c * 8 + 0] + q1 * kr[c * 8 + 1] +
                     q2 * kr[c * 8 + 2] + q3 * kr[c * 8 + 3] +
                     q4 * kr[c * 8 + 4] + q5 * kr[c * 8 + 5] +
                     q6 * kr[c * 8 + 6] + q7 * kr[c * 8 + 7];
            }
            Sc[t * L_ + s] = d * 0.125f;
        }
    }
    __syncthreads();

    {
        int t = tid >> 3, j = tid & 7;
        float m = -1e30f;
        for (int s = j * 32; s < j * 32 + 32; ++s) m = fmaxf(m, Sc[t * L_ + s]);
        red8[t][j] = m;
    }
    __syncthreads();
    if (tid < T_) {
        float m = red8[tid][0];
#pragma unroll
        for (int j = 1; j < 8; ++j) m = fmaxf(m, red8[tid][j]);
        mx[tid] = m;
    }
    __syncthreads();
    {
        int t = tid >> 3, j = tid & 7;
        float m = mx[t], sum = 0.f;
        for (int s = j * 32; s < j * 32 + 32; ++s) {
            float e = expf(Sc[t * L_ + s] - m);
            Sc[t * L_ + s] = e;
            sum += e;
        }
        red8[t][j] = sum;
    }
    __syncthreads();
    if (tid < T_) {
        float s = 0.f;
#pragma unroll
        for (int j = 0; j < 8; ++j) s += red8[tid][j];
        dn[tid] = 1.f / s;
    }
    __syncthreads();

    {
        int t = tid >> 3, c = tid & 7;
        float o[8] = {};
        for (int si = 0; si < L_; ++si) {
            int s = (si + t * 33) & (L_ - 1);
            float p = Sc[t * L_ + s];
            int cp = (c ^ (s & 7)) * 8;
            uint4 u = *(const uint4*)&Vs[s * 64 + cp];
            float v0, v1, v2, v3, v4, v5, v6, v7;
            unpack2(u.x, v0, v1); unpack2(u.y, v2, v3);
            unpack2(u.z, v4, v5); unpack2(u.w, v6, v7);
            o[0] += p * v0; o[1] += p * v1; o[2] += p * v2; o[3] += p * v3;
            o[4] += p * v4; o[5] += p * v5; o[6] += p * v6; o[7] += p * v7;
        }
        float sc = dn[t];
        ushort8v pk;
#pragma unroll
        for (int j = 0; j < 8; ++j) pk[j] = f2bf(o[j] * sc);
        *(ushort8v*)(ctx + (size_t)(b * T_ + t) * E_ + h * HD_ + c * 8) = pk;
    }
}

extern "C" void kernel_launch(void* const* d_in, const int* in_sizes, int n_in,
                              void* d_out, int out_size, void* d_ws, size_t ws_size,
                              hipStream_t stream) {
    const float* enc      = (const float*)d_in[0];
    const float* qe       = (const float*)d_in[1];
    const float* pos      = (const float*)d_in[2];
    const float* m_norm_w = (const float*)d_in[3];
    const float* m_in_w   = (const float*)d_in[4];
    const float* m_conv_w = (const float*)d_in[5];
    const float* m_conv_b = (const float*)d_in[6];
    const float* m_xproj_w= (const float*)d_in[7];
    const float* m_dt_w   = (const float*)d_in[8];
    const float* m_dt_b   = (const float*)d_in[9];
    const float* m_Alog   = (const float*)d_in[10];
    const float* m_D      = (const float*)d_in[11];
    const float* m_out_w  = (const float*)d_in[12];
    const float* rms_w    = (const float*)d_in[13];
    const float* wq = (const float*)d_in[14];
    const float* bq = (const float*)d_in[15];
    const float* wk = (const float*)d_in[16];
    const float* bk = (const float*)d_in[17];
    const float* wv = (const float*)d_in[18];
    const float* bv = (const float*)d_in[19];
    const float* wo = (const float*)d_in[20];
    const float* bo = (const float*)d_in[21];
    const float* ln1_w = (const float*)d_in[22];
    const float* ln1_b = (const float*)d_in[23];
    const float* ffn_w1 = (const float*)d_in[24];
    const float* ffn_b1 = (const float*)d_in[25];
    const float* ffn_w2 = (const float*)d_in[26];
    const float* ffn_b2 = (const float*)d_in[27];
    const float* ln2_w = (const float*)d_in[28];
    const float* ln2_b = (const float*)d_in[29];
    const float* out_w = (const float*)d_in[30];
    const float* out_b = (const float*)d_in[31];

    // ---- workspace layout ----
    float* residual = (float*)d_ws;                  // 786,432 f
    float* dtwT  = residual + 786432;                // 221,184 f
    float* negAT = dtwT + 221184;                    // 147,456 f
    float* kvb   = negAT + 147456;                   //     768 f
    ushort_t* U = (ushort_t*)(kvb + 768);
    ushort_t* enc_bf = U;                            // 6,291,456
    ushort_t* xz   = enc_bf + 6291456;               // 3,145,728
    ushort_t* yb   = xz + 3145728;                   // 1,572,864
    ushort_t* qh   = yb + 1572864;                   //   786,432
    ushort_t* ctx  = qh + 786432;                    //   786,432
    ushort_t* khv  = ctx + 786432;                   // 12,582,912
    ushort_t* ffnb = khv + 12582912;                 // 3,145,728
    ushort_t* w_in  = ffnb + 3145728;                // 7,077,888
    ushort_t* w_xp  = w_in + 7077888;                //   589,824
    ushort_t* w_out = w_xp + 589824;                 // 3,538,944
    ushort_t* w_q   = w_out + 3538944;               //   147,456
    ushort_t* w_k   = w_q + 147456;                  //   147,456
    ushort_t* w_v   = w_k + 147456;                  //   147,456 (adjacent to w_k)
    ushort_t* w_o   = w_v + 147456;                  //   147,456
    ushort_t* w_f1  = w_o + 147456;                  //   589,824
    ushort_t* w_f2  = w_f1 + 589824;                 //   589,824
    ushort_t* w_lg  = w_f2 + 589824;                 //    49,152

    const int M = B_ * T_;   // 2048
    const int MK = B_ * L_;  // 16384

    prep_kernel<<<(int)((PREP_TOTAL + 255) / 256), 256, 0, stream>>>(
        m_in_w, m_xproj_w, m_out_w, wq, wk, wv, wo, ffn_w1, ffn_w2, out_w,
        m_dt_w, m_Alog, enc, bk, bv,
        w_in, w_xp, w_out, w_q, w_k, w_v, w_o, w_f1, w_f2, w_lg,
        dtwT, negAT, enc_bf, kvb);

    init_kernel<<<(M * E_ + 255) / 256, 256, 0, stream>>>(qe, pos, residual);

    for (int l = 0; l < ND_; ++l) {
        // rmsnorm + in_proj + z-silu -> xz
        fused_gemm<0, 3, 1><<<dim3(M / 64, 24), 256, 0, stream>>>(
            residual, m_norm_w + (size_t)l * 384, nullptr,
            w_in + (size_t)l * 1536 * 384, nullptr, xz, 1536, 1536);
        // conv + xproj + dt + scan + gate -> yb
        convscan_kernel<<<B_, 768, 0, stream>>>(
            xz, m_conv_w + (size_t)l * 768 * 4, m_conv_b + (size_t)l * 768,
            w_xp + (size_t)l * 64 * 768, dtwT + (size_t)l * 24 * 768,
            m_dt_b + (size_t)l * 768, negAT + (size_t)l * 16 * 768,
            m_D + (size_t)l * 768, yb);
        // out_proj, residual += yb @ Wo^T
        gemm_bf16<0><<<dim3(M / 64, 6), 256, 0, stream>>>(
            yb, 768, w_out + (size_t)l * 384 * 768, nullptr, residual,
            residual, M, 384, 768, 384);
    }

    // final rmsnorm + q-proj
    fused_gemm<0, 0, 1><<<dim3(M / 64, 6), 256, 0, stream>>>(
        residual, rms_w, nullptr, w_q, bq, qh, 384, 384);
    // combined k|v projection (weights adjacent), N=768
    gemm_bf16<1><<<dim3(MK / 64, 12), 256, 0, stream>>>(
        enc_bf, 384, w_k, kvb, nullptr, khv, MK, 768, 384, 768);
    attn_kernel<<<B_ * H_, 256, 0, stream>>>(qh, khv, ctx);
    // o-proj, residual += ctx @ Wo^T
    gemm_bf16<0><<<dim3(M / 64, 6), 256, 0, stream>>>(
        ctx, 384, w_o, bo, residual, residual, M, 384, 384, 384);
    // ln1 + ffn1 + relu
    fused_gemm<1, 1, 1><<<dim3(M / 64, 24), 256, 0, stream>>>(
        residual, ln1_w, ln1_b, w_f1, ffn_b1, ffnb, 1536, 1536);
    // ffn2, residual +=
    gemm_bf16<0><<<dim3(M / 64, 6), 256, 0, stream>>>(
        ffnb, 1536, w_f2, ffn_b2, residual, residual, M, 384, 1536, 384);
    // ln2 + logits (fp32 out)
    fused_gemm<1, 0, 0><<<dim3(M / 64, 2), 256, 0, stream>>>(
        residual, ln2_w, ln2_b, w_lg, out_b, (float*)d_out, 97, 97);
}

// Round 7
// 1796.380 us; speedup vs baseline: 1.4794x; 1.0978x over previous
//
#include <hip/hip_runtime.h>
#include <math.h>

// ---- problem constants ----
constexpr int B_ = 64, L_ = 256, T_ = 32, E_ = 384, H_ = 6;
constexpr int DI_ = 768, DS_ = 16, DC_ = 4, DR_ = 24;
constexpr int HID_ = 1536, V_ = 97, ND_ = 12;
constexpr float EPS_ = 1e-5f;
constexpr int HD_ = 64;

typedef unsigned short ushort_t;
typedef __attribute__((ext_vector_type(8))) short  short8;
typedef __attribute__((ext_vector_type(4))) float  floatx4;
typedef __attribute__((ext_vector_type(4))) unsigned short ushort4v;
typedef __attribute__((ext_vector_type(8))) unsigned short ushort8v;

__device__ __forceinline__ float siluf(float x) { return x / (1.f + expf(-x)); }
__device__ __forceinline__ float softplusf(float x) {
    return fmaxf(x, 0.f) + log1pf(expf(-fabsf(x)));
}
__device__ __forceinline__ ushort_t f2bf(float f) {
    unsigned int u = __float_as_uint(f);
    u += 0x7fffu + ((u >> 16) & 1u);
    return (ushort_t)(u >> 16);
}
__device__ __forceinline__ float bf2f(ushort_t u) {
    return __uint_as_float(((unsigned int)u) << 16);
}
__device__ __forceinline__ void unpack2(unsigned int w, float& lo, float& hi) {
    lo = __uint_as_float(w << 16);
    hi = __uint_as_float(w & 0xffff0000u);
}
// async global->LDS, 16B/lane; dest = wave-uniform base + lane*16
__device__ __forceinline__ void gl_lds16(const ushort_t* g, ushort_t* l) {
    __builtin_amdgcn_global_load_lds(
        (const __attribute__((address_space(1))) unsigned int*)g,
        (__attribute__((address_space(3))) unsigned int*)l, 16, 0, 0);
}

// ---------------------------------------------------------------------------
// one-shot prep: weight bf16 conversions (+pad), transposes, enc cvt, kv bias
// ---------------------------------------------------------------------------
__global__ __launch_bounds__(256) void prep_kernel(
    const float* __restrict__ m_in_w, const float* __restrict__ m_xproj_w,
    const float* __restrict__ m_out_w,
    const float* __restrict__ wq, const float* __restrict__ wk,
    const float* __restrict__ wvv, const float* __restrict__ wo,
    const float* __restrict__ f1, const float* __restrict__ f2,
    const float* __restrict__ out_w,
    const float* __restrict__ m_dt_w, const float* __restrict__ m_Alog,
    const float* __restrict__ enc,
    const float* __restrict__ bk, const float* __restrict__ bv,
    ushort_t* __restrict__ w_in, ushort_t* __restrict__ w_xp,
    ushort_t* __restrict__ w_out_,
    ushort_t* __restrict__ w_q, ushort_t* __restrict__ w_k,
    ushort_t* __restrict__ w_v, ushort_t* __restrict__ w_o,
    ushort_t* __restrict__ w_f1, ushort_t* __restrict__ w_f2,
    ushort_t* __restrict__ w_lg,
    float* __restrict__ dtwT, float* __restrict__ negAT,
    ushort_t* __restrict__ enc_bf, float* __restrict__ kvb) {
    long i = (long)blockIdx.x * 256 + threadIdx.x;
    if (i < 7077888) { w_in[i] = f2bf(m_in_w[i]); return; } i -= 7077888;
    if (i < 589824) {
        int l = (int)(i / (64 * 768)); int rem = (int)(i % (64 * 768));
        int r = rem / 768, c = rem % 768;
        w_xp[i] = (r < 56) ? f2bf(m_xproj_w[((size_t)l * 56 + r) * 768 + c])
                           : (ushort_t)0;
        return; } i -= 589824;
    if (i < 3538944) { w_out_[i] = f2bf(m_out_w[i]); return; } i -= 3538944;
    if (i < 147456) { w_q[i] = f2bf(wq[i]); return; } i -= 147456;
    if (i < 147456) { w_k[i] = f2bf(wk[i]); return; } i -= 147456;
    if (i < 147456) { w_v[i] = f2bf(wvv[i]); return; } i -= 147456;
    if (i < 147456) { w_o[i] = f2bf(wo[i]); return; } i -= 147456;
    if (i < 589824) { w_f1[i] = f2bf(f1[i]); return; } i -= 589824;
    if (i < 589824) { w_f2[i] = f2bf(f2[i]); return; } i -= 589824;
    if (i < 49152) {
        int r = (int)(i / 384), c = (int)(i % 384);
        w_lg[i] = (r < 97) ? f2bf(out_w[r * 384 + c]) : (ushort_t)0;
        return; } i -= 49152;
    if (i < 221184) {  // dtwT [12][24][768] <- m_dt_w [12][768][24]
        int l = (int)(i / (24 * 768)); int rem = (int)(i % (24 * 768));
        int r = rem / 768, d = rem % 768;
        dtwT[i] = m_dt_w[((size_t)l * 768 + d) * 24 + r];
        return; } i -= 221184;
    if (i < 147456) {  // negAT [12][16][768] = -exp(Alog)
        int l = (int)(i / (16 * 768)); int rem = (int)(i % (16 * 768));
        int s = rem / 768, d = rem % 768;
        negAT[i] = -expf(m_Alog[((size_t)l * 768 + d) * 16 + s]);
        return; } i -= 147456;
    if (i < 6291456) { enc_bf[i] = f2bf(enc[i]); return; } i -= 6291456;
    if (i < 768) { kvb[i] = (i < 384) ? bk[i] : bv[i - 384]; return; }
}
constexpr long PREP_TOTAL = 7077888L + 589824 + 3538944 + 4 * 147456
    + 2 * 589824 + 49152 + 221184 + 147456 + 6291456 + 768;

// ---------------------------------------------------------------------------
// init: res = qe + pos (broadcast over B)
// ---------------------------------------------------------------------------
__global__ void init_kernel(const float* __restrict__ qe,
                            const float* __restrict__ pos,
                            float* __restrict__ res) {
    long idx = (long)blockIdx.x * 256 + threadIdx.x;
    if (idx >= (long)B_ * T_ * E_) return;
    int te = (int)(idx % ((long)T_ * E_));
    res[idx] = qe[te] + pos[te];
}

// ---------------------------------------------------------------------------
// in_proj with fused rmsnorm prologue and fused conv+silu epilogue.
// grid (32, 24): bn<12 -> xm half (conv+silu -> xc); bn>=12 -> silu(z) -> zb.
// ---------------------------------------------------------------------------
__global__ __launch_bounds__(256) void fused_in_proj(
    const float* __restrict__ res, const float* __restrict__ nw,
    const ushort_t* __restrict__ W,
    const float* __restrict__ cw, const float* __restrict__ cb,
    ushort_t* __restrict__ xc, ushort_t* __restrict__ zb) {
    __shared__ ushort_t Apan[64 * 384];  // 48 KB (reused as conv tile in epi)
    __shared__ ushort_t Bs[64 * 64];     // 8 KB

    const int tid = threadIdx.x;
    const int wv = tid >> 6, ln = tid & 63;
    const int bm = blockIdx.x * 64, bn = blockIdx.y * 64;
    const int lm = ln & 15, quad = ln >> 4;
    const int wm = (wv & 1) * 32, wn = (wv >> 1) * 32;
    const int r8 = ln >> 3, c8 = ln & 7;

    // ---- prologue: per-row rmsnorm + bf16 A panel (4 threads/row) ----
    {
        const int r = tid >> 2, cq = tid & 3;
        const float* rp = res + (size_t)(bm + r) * 384 + cq * 96;
        float s2 = 0.f;
#pragma unroll 4
        for (int i = 0; i < 24; ++i) {
            float4 v = ((const float4*)rp)[i];
            s2 += v.x * v.x + v.y * v.y + v.z * v.z + v.w * v.w;
        }
        s2 += __shfl_xor(s2, 1); s2 += __shfl_xor(s2, 2);
        float sc = rsqrtf(s2 * (1.f / 384.f) + EPS_);
#pragma unroll 4
        for (int i = 0; i < 24; ++i) {
            float4 v = ((const float4*)rp)[i];
            int col = cq * 96 + i * 4;
            ushort4v pk;
            pk[0] = f2bf(v.x * sc * nw[col + 0]);
            pk[1] = f2bf(v.y * sc * nw[col + 1]);
            pk[2] = f2bf(v.z * sc * nw[col + 2]);
            pk[3] = f2bf(v.w * sc * nw[col + 3]);
            int chunk = col >> 3;
            *(ushort4v*)&Apan[r * 384 + (((chunk ^ (r & 7)) << 3) | (col & 7))] = pk;
        }
    }

    floatx4 acc[2][2] = {};

    for (int k0 = 0; k0 < 384; k0 += 64) {
#pragma unroll
        for (int j = 0; j < 2; ++j) {
            int row = wv * 16 + j * 8 + r8;
            int cg = c8 ^ (row & 7);
            gl_lds16(W + (size_t)(bn + row) * 384 + k0 + cg * 8,
                     &Bs[(wv * 16 + j * 8) * 64]);
        }
        __syncthreads();
#pragma unroll
        for (int ks2 = 0; ks2 < 2; ++ks2) {
            int sub = ks2 * 4 + quad;
            int ra0 = wm + lm, ra1 = wm + 16 + lm;
            int ca0 = ((k0 >> 3) + (sub ^ (ra0 & 7))) << 3;
            int ca1 = ((k0 >> 3) + (sub ^ (ra1 & 7))) << 3;
            short8 a0 = *(const short8*)&Apan[ra0 * 384 + ca0];
            short8 a1 = *(const short8*)&Apan[ra1 * 384 + ca1];
            int pc = (sub ^ (lm & 7)) * 8;
            short8 b0 = *(const short8*)&Bs[(wn + lm) * 64 + pc];
            short8 b1 = *(const short8*)&Bs[(wn + 16 + lm) * 64 + pc];
            acc[0][0] = __builtin_amdgcn_mfma_f32_16x16x32_bf16(a0, b0, acc[0][0], 0, 0, 0);
            acc[0][1] = __builtin_amdgcn_mfma_f32_16x16x32_bf16(a0, b1, acc[0][1], 0, 0, 0);
            acc[1][0] = __builtin_amdgcn_mfma_f32_16x16x32_bf16(a1, b0, acc[1][0], 0, 0, 0);
            acc[1][1] = __builtin_amdgcn_mfma_f32_16x16x32_bf16(a1, b1, acc[1][1], 0, 0, 0);
        }
        __syncthreads();
    }

    // C/D layout: col = lane&15, row = quad*4 + reg  [m89-verified]
    if (blockIdx.y < 12) {
        // xm half: stash tile in LDS (reuse Apan), then conv+silu -> xc
#pragma unroll
        for (int sm_ = 0; sm_ < 2; ++sm_)
#pragma unroll
            for (int sn = 0; sn < 2; ++sn) {
                int col = wn + sn * 16 + lm;
#pragma unroll
                for (int r = 0; r < 4; ++r) {
                    int row = wm + sm_ * 16 + quad * 4 + r;
                    Apan[row * 72 + col] = f2bf(acc[sm_][sn][r]);
                }
            }
        __syncthreads();
        const int j = ln;            // column in tile
        const int gn = bn + j;
        const float4 c4 = *(const float4*)(cw + gn * 4);
        const float cb0 = cb[gn];
#pragma unroll 4
        for (int i = 0; i < 16; ++i) {
            int m = wv * 16 + i;
            int t = m & 31;
            float a = cb0;
#pragma unroll
            for (int k = 0; k < 4; ++k) {
                if (t + k - 3 >= 0) {
                    float xv = bf2f(Apan[(m + k - 3) * 72 + j]);
                    float wv_ = (k == 0) ? c4.x : (k == 1) ? c4.y
                              : (k == 2) ? c4.z : c4.w;
                    a += wv_ * xv;
                }
            }
            xc[(size_t)(bm + m) * 768 + gn] = f2bf(siluf(a));
        }
    } else {
        // z half: silu -> zb
#pragma unroll
        for (int sm_ = 0; sm_ < 2; ++sm_)
#pragma unroll
            for (int sn = 0; sn < 2; ++sn) {
                int gn = bn + wn + sn * 16 + lm - 768;
#pragma unroll
                for (int r = 0; r < 4; ++r) {
                    int gm = bm + wm + sm_ * 16 + quad * 4 + r;
                    zb[(size_t)gm * 768 + gn] = f2bf(siluf(acc[sm_][sn][r]));
                }
            }
    }
}

// ---------------------------------------------------------------------------
// plain 64x64 bf16 GEMM (proven). A bf16 [M][lda].
// ---------------------------------------------------------------------------
template <int OBF>
__global__ __launch_bounds__(256) void gemm_bf16(
    const ushort_t* __restrict__ A, int lda,
    const ushort_t* __restrict__ W,
    const float* __restrict__ bias,
    const float* __restrict__ addin,
    void* __restrict__ Cv,
    int M, int N, int K, int ldc) {
    __shared__ ushort_t As[64 * 64];
    __shared__ ushort_t Bs[64 * 64];

    const int tid = threadIdx.x;
    const int wv = tid >> 6, ln = tid & 63;
    const int bm = blockIdx.x * 64, bn = blockIdx.y * 64;
    const int lm = ln & 15, quad = ln >> 4;
    const int wm = (wv & 1) * 32, wn = (wv >> 1) * 32;
    const int r8 = ln >> 3, c8 = ln & 7;

    floatx4 acc[2][2] = {};

    for (int k0 = 0; k0 < K; k0 += 64) {
#pragma unroll
        for (int j = 0; j < 2; ++j) {
            int row = wv * 16 + j * 8 + r8;
            int cg = c8 ^ (row & 7);
            gl_lds16(A + (size_t)(bm + row) * lda + k0 + cg * 8,
                     &As[(wv * 16 + j * 8) * 64]);
        }
#pragma unroll
        for (int j = 0; j < 2; ++j) {
            int row = wv * 16 + j * 8 + r8;
            int cg = c8 ^ (row & 7);
            gl_lds16(W + (size_t)(bn + row) * K + k0 + cg * 8,
                     &Bs[(wv * 16 + j * 8) * 64]);
        }
        __syncthreads();
#pragma unroll
        for (int ks2 = 0; ks2 < 2; ++ks2) {
            int pc = ((quad + ks2 * 4) ^ (lm & 7)) * 8;
            short8 a0 = *(const short8*)&As[(wm + lm) * 64 + pc];
            short8 a1 = *(const short8*)&As[(wm + 16 + lm) * 64 + pc];
            short8 b0 = *(const short8*)&Bs[(wn + lm) * 64 + pc];
            short8 b1 = *(const short8*)&Bs[(wn + 16 + lm) * 64 + pc];
            acc[0][0] = __builtin_amdgcn_mfma_f32_16x16x32_bf16(a0, b0, acc[0][0], 0, 0, 0);
            acc[0][1] = __builtin_amdgcn_mfma_f32_16x16x32_bf16(a0, b1, acc[0][1], 0, 0, 0);
            acc[1][0] = __builtin_amdgcn_mfma_f32_16x16x32_bf16(a1, b0, acc[1][0], 0, 0, 0);
            acc[1][1] = __builtin_amdgcn_mfma_f32_16x16x32_bf16(a1, b1, acc[1][1], 0, 0, 0);
        }
        __syncthreads();
    }

#pragma unroll
    for (int sm_ = 0; sm_ < 2; ++sm_) {
#pragma unroll
        for (int sn = 0; sn < 2; ++sn) {
            const int gn = bn + wn + sn * 16 + lm;
            if (gn >= N) continue;
#pragma unroll
            for (int r = 0; r < 4; ++r) {
                const int gm = bm + wm + sm_ * 16 + quad * 4 + r;
                float v = acc[sm_][sn][r];
                if (bias) v += bias[gn];
                if (addin) v += addin[(size_t)gm * ldc + gn];
                if (OBF)
                    ((ushort_t*)Cv)[(size_t)gm * ldc + gn] = f2bf(v);
                else
                    ((float*)Cv)[(size_t)gm * ldc + gn] = v;
            }
        }
    }
}

// ---------------------------------------------------------------------------
// Norm-fused GEMM (round-6 proven), K=384 fixed. For q/ffn1/logits.
// NORM: 0 rmsnorm, 1 layernorm. EPI: 0 plain, 1 relu. OBF: 1 bf16, 0 fp32.
// ---------------------------------------------------------------------------
template <int NORM, int EPI, int OBF>
__global__ __launch_bounds__(256) void fused_gemm(
    const float* __restrict__ res,
    const float* __restrict__ nw, const float* __restrict__ nb,
    const ushort_t* __restrict__ W,
    const float* __restrict__ bias,
    void* __restrict__ Cv, int N, int ldc) {
    __shared__ ushort_t Apan[64 * 384];
    __shared__ ushort_t Bs[64 * 64];

    const int tid = threadIdx.x;
    const int wv = tid >> 6, ln = tid & 63;
    const int bm = blockIdx.x * 64, bn = blockIdx.y * 64;
    const int lm = ln & 15, quad = ln >> 4;
    const int wm = (wv & 1) * 32, wn = (wv >> 1) * 32;
    const int r8 = ln >> 3, c8 = ln & 7;

    {
        const int r = tid >> 2, cq = tid & 3;
        const float* rp = res + (size_t)(bm + r) * 384 + cq * 96;
        float s = 0.f, s2 = 0.f;
#pragma unroll 4
        for (int i = 0; i < 24; ++i) {
            float4 v = ((const float4*)rp)[i];
            if (NORM == 1) s += v.x + v.y + v.z + v.w;
            s2 += v.x * v.x + v.y * v.y + v.z * v.z + v.w * v.w;
        }
        if (NORM == 1) { s += __shfl_xor(s, 1); s += __shfl_xor(s, 2); }
        s2 += __shfl_xor(s2, 1); s2 += __shfl_xor(s2, 2);
        float mu = (NORM == 1) ? s * (1.f / 384.f) : 0.f;
        float var = (NORM == 1) ? s2 * (1.f / 384.f) - mu * mu
                                : s2 * (1.f / 384.f);
        float sc = rsqrtf(var + EPS_);
#pragma unroll 4
        for (int i = 0; i < 24; ++i) {
            float4 v = ((const float4*)rp)[i];
            int col = cq * 96 + i * 4;
            float o0 = (v.x - mu) * sc * nw[col + 0];
            float o1 = (v.y - mu) * sc * nw[col + 1];
            float o2 = (v.z - mu) * sc * nw[col + 2];
            float o3 = (v.w - mu) * sc * nw[col + 3];
            if (NORM == 1) {
                o0 += nb[col + 0]; o1 += nb[col + 1];
                o2 += nb[col + 2]; o3 += nb[col + 3];
            }
            ushort4v pk;
            pk[0] = f2bf(o0); pk[1] = f2bf(o1); pk[2] = f2bf(o2); pk[3] = f2bf(o3);
            int chunk = col >> 3;
            *(ushort4v*)&Apan[r * 384 + (((chunk ^ (r & 7)) << 3) | (col & 7))] = pk;
        }
    }

    floatx4 acc[2][2] = {};

    for (int k0 = 0; k0 < 384; k0 += 64) {
#pragma unroll
        for (int j = 0; j < 2; ++j) {
            int row = wv * 16 + j * 8 + r8;
            int cg = c8 ^ (row & 7);
            gl_lds16(W + (size_t)(bn + row) * 384 + k0 + cg * 8,
                     &Bs[(wv * 16 + j * 8) * 64]);
        }
        __syncthreads();
#pragma unroll
        for (int ks2 = 0; ks2 < 2; ++ks2) {
            int sub = ks2 * 4 + quad;
            int ra0 = wm + lm, ra1 = wm + 16 + lm;
            int ca0 = ((k0 >> 3) + (sub ^ (ra0 & 7))) << 3;
            int ca1 = ((k0 >> 3) + (sub ^ (ra1 & 7))) << 3;
            short8 a0 = *(const short8*)&Apan[ra0 * 384 + ca0];
            short8 a1 = *(const short8*)&Apan[ra1 * 384 + ca1];
            int pc = (sub ^ (lm & 7)) * 8;
            short8 b0 = *(const short8*)&Bs[(wn + lm) * 64 + pc];
            short8 b1 = *(const short8*)&Bs[(wn + 16 + lm) * 64 + pc];
            acc[0][0] = __builtin_amdgcn_mfma_f32_16x16x32_bf16(a0, b0, acc[0][0], 0, 0, 0);
            acc[0][1] = __builtin_amdgcn_mfma_f32_16x16x32_bf16(a0, b1, acc[0][1], 0, 0, 0);
            acc[1][0] = __builtin_amdgcn_mfma_f32_16x16x32_bf16(a1, b0, acc[1][0], 0, 0, 0);
            acc[1][1] = __builtin_amdgcn_mfma_f32_16x16x32_bf16(a1, b1, acc[1][1], 0, 0, 0);
        }
        __syncthreads();
    }

#pragma unroll
    for (int sm_ = 0; sm_ < 2; ++sm_) {
#pragma unroll
        for (int sn = 0; sn < 2; ++sn) {
            const int gn = bn + wn + sn * 16 + lm;
            if (gn >= N) continue;
#pragma unroll
            for (int r = 0; r < 4; ++r) {
                const int gm = bm + wm + sm_ * 16 + quad * 4 + r;
                float v = acc[sm_][sn][r];
                if (bias) v += bias[gn];
                if (EPI == 1) v = fmaxf(v, 0.f);
                if (OBF)
                    ((ushort_t*)Cv)[(size_t)gm * ldc + gn] = f2bf(v);
                else
                    ((float*)Cv)[(size_t)gm * ldc + gn] = v;
            }
        }
    }
}

// ---------------------------------------------------------------------------
// selective scan with fused dt-proj. grid (12, 64), 64 threads (1 wave).
// thread owns chain (b, d). dbl staged per block (broadcast reads).
// ---------------------------------------------------------------------------
__global__ __launch_bounds__(64) void scan_kernel(
    const ushort_t* __restrict__ dblG,   // [2048][64] bf16 (cols 0..55 valid)
    const ushort_t* __restrict__ xc,     // [2048][768] bf16
    const ushort_t* __restrict__ zb,     // [2048][768] bf16 (silu'd)
    const float* __restrict__ dT,        // [24][768] layer slice
    const float* __restrict__ db_,       // [768]
    const float* __restrict__ nA_,       // [16][768]
    const float* __restrict__ Dp_,       // [768]
    ushort_t* __restrict__ yb) {         // [2048][768] bf16
    __shared__ float dblS[32 * 64];
    const int ln = threadIdx.x;
    const int b = blockIdx.y;
    const int d = blockIdx.x * 64 + ln;

    for (int i = ln; i < 2048; i += 64)
        dblS[i] = bf2f(dblG[(size_t)b * 32 * 64 + i]);
    __syncthreads();

    float wr[DR_];
#pragma unroll
    for (int r = 0; r < DR_; ++r) wr[r] = dT[r * 768 + d];
    const float dtb0 = db_[d];
    float nA[DS_];
#pragma unroll
    for (int s = 0; s < DS_; ++s) nA[s] = nA_[s * 768 + d];
    const float Dv = Dp_[d];
    float h[DS_] = {};

    for (int t = 0; t < T_; ++t) {
        float dtv = dtb0;
#pragma unroll
        for (int r = 0; r < DR_; ++r) dtv += dblS[t * 64 + r] * wr[r];
        dtv = softplusf(dtv);
        size_t rowb = (size_t)(b * 32 + t) * 768 + d;
        float xcv = bf2f(xc[rowb]);
        float a = 0.f;
#pragma unroll
        for (int s = 0; s < DS_; ++s) {
            h[s] = expf(dtv * nA[s]) * h[s] + dtv * dblS[t * 64 + 24 + s] * xcv;
            a += h[s] * dblS[t * 64 + 40 + s];
        }
        float zv = bf2f(zb[rowb]);
        yb[rowb] = f2bf((a + Dv * xcv) * zv);
    }
}

// ---------------------------------------------------------------------------
// cross-attention, one block per (b,h). khv combined layout [b*L][768].
// ---------------------------------------------------------------------------
__global__ __launch_bounds__(256) void attn_kernel(
    const ushort_t* __restrict__ qh,
    const ushort_t* __restrict__ khv,
    ushort_t* __restrict__ ctx) {
    const int h = blockIdx.x % H_;
    const int b = blockIdx.x / H_;
    const int tid = threadIdx.x;

    __shared__ ushort_t Ks[L_ * HD_];
    __shared__ ushort_t Vs[L_ * HD_];
    __shared__ ushort_t Qs[T_ * HD_];
    __shared__ float Sc[T_ * L_];
    __shared__ float red8[T_][8];
    __shared__ float mx[T_], dn[T_];

    {
        int t = tid >> 3, c = tid & 7;
        *(uint4*)&Qs[t * 64 + c * 8] =
            *(const uint4*)(qh + (size_t)(b * T_ + t) * E_ + h * HD_ + c * 8);
    }
    {
        int s = tid;
        const ushort_t* kr = khv + (size_t)(b * L_ + s) * 768 + h * HD_;
        const ushort_t* vr = kr + 384;
#pragma unroll
        for (int c = 0; c < 8; ++c) {
            int cp = (c ^ (s & 7)) * 8;
            *(uint4*)&Ks[s * 64 + cp] = *(const uint4*)(kr + c * 8);
            *(uint4*)&Vs[s * 64 + cp] = *(const uint4*)(vr + c * 8);
        }
    }
    __syncthreads();

    {
        int s = tid;
        float kr[64];
#pragma unroll
        for (int c = 0; c < 8; ++c) {
            int cp = (c ^ (s & 7)) * 8;
            uint4 u = *(const uint4*)&Ks[s * 64 + cp];
            unpack2(u.x, kr[c * 8 + 0], kr[c * 8 + 1]);
            unpack2(u.y, kr[c * 8 + 2], kr[c * 8 + 3]);
            unpack2(u.z, kr[c * 8 + 4], kr[c * 8 + 5]);
            unpack2(u.w, kr[c * 8 + 6], kr[c * 8 + 7]);
        }
        for (int t = 0; t < T_; ++t) {
            float d = 0.f;
#pragma unroll
            for (int c = 0; c < 8; ++c) {
                uint4 qu = *(const uint4*)&Qs[t * 64 + c * 8];
                float q0, q1, q2, q3, q4, q5, q6, q7;
                unpack2(qu.x, q0, q1); unpack2(qu.y, q2, q3);
                unpack2(qu.z, q4, q5); unpack2(qu.w, q6, q7);
                d += q0 * kr[c * 8 + 0] + q1 * kr[c * 8 + 1] +
                     q2 * kr[c * 8 + 2] + q3 * kr[c * 8 + 3] +
                     q4 * kr[c * 8 + 4] + q5 * kr[c * 8 + 5] +
                     q6 * kr[c * 8 + 6] + q7 * kr[c * 8 + 7];
            }
            Sc[t * L_ + s] = d * 0.125f;
        }
    }
    __syncthreads();

    {
        int t = tid >> 3, j = tid & 7;
        float m = -1e30f;
        for (int s = j * 32; s < j * 32 + 32; ++s) m = fmaxf(m, Sc[t * L_ + s]);
        red8[t][j] = m;
    }
    __syncthreads();
    if (tid < T_) {
        float m = red8[tid][0];
#pragma unroll
        for (int j = 1; j < 8; ++j) m = fmaxf(m, red8[tid][j]);
        mx[tid] = m;
    }
    __syncthreads();
    {
        int t = tid >> 3, j = tid & 7;
        float m = mx[t], sum = 0.f;
        for (int s = j * 32; s < j * 32 + 32; ++s) {
            float e = expf(Sc[t * L_ + s] - m);
            Sc[t * L_ + s] = e;
            sum += e;
        }
        red8[t][j] = sum;
    }
    __syncthreads();
    if (tid < T_) {
        float s = 0.f;
#pragma unroll
        for (int j = 0; j < 8; ++j) s += red8[tid][j];
        dn[tid] = 1.f / s;
    }
    __syncthreads();

    {
        int t = tid >> 3, c = tid & 7;
        float o[8] = {};
        for (int si = 0; si < L_; ++si) {
            int s = (si + t * 33) & (L_ - 1);
            float p = Sc[t * L_ + s];
            int cp = (c ^ (s & 7)) * 8;
            uint4 u = *(const uint4*)&Vs[s * 64 + cp];
            float v0, v1, v2, v3, v4, v5, v6, v7;
            unpack2(u.x, v0, v1); unpack2(u.y, v2, v3);
            unpack2(u.z, v4, v5); unpack2(u.w, v6, v7);
            o[0] += p * v0; o[1] += p * v1; o[2] += p * v2; o[3] += p * v3;
            o[4] += p * v4; o[5] += p * v5; o[6] += p * v6; o[7] += p * v7;
        }
        float sc = dn[t];
        ushort8v pk;
#pragma unroll
        for (int j = 0; j < 8; ++j) pk[j] = f2bf(o[j] * sc);
        *(ushort8v*)(ctx + (size_t)(b * T_ + t) * E_ + h * HD_ + c * 8) = pk;
    }
}

extern "C" void kernel_launch(void* const* d_in, const int* in_sizes, int n_in,
                              void* d_out, int out_size, void* d_ws, size_t ws_size,
                              hipStream_t stream) {
    const float* enc      = (const float*)d_in[0];
    const float* qe       = (const float*)d_in[1];
    const float* pos      = (const float*)d_in[2];
    const float* m_norm_w = (const float*)d_in[3];
    const float* m_in_w   = (const float*)d_in[4];
    const float* m_conv_w = (const float*)d_in[5];
    const float* m_conv_b = (const float*)d_in[6];
    const float* m_xproj_w= (const float*)d_in[7];
    const float* m_dt_w   = (const float*)d_in[8];
    const float* m_dt_b   = (const float*)d_in[9];
    const float* m_Alog   = (const float*)d_in[10];
    const float* m_D      = (const float*)d_in[11];
    const float* m_out_w  = (const float*)d_in[12];
    const float* rms_w    = (const float*)d_in[13];
    const float* wq = (const float*)d_in[14];
    const float* bq = (const float*)d_in[15];
    const float* wk = (const float*)d_in[16];
    const float* bk = (const float*)d_in[17];
    const float* wv = (const float*)d_in[18];
    const float* bv = (const float*)d_in[19];
    const float* wo = (const float*)d_in[20];
    const float* bo = (const float*)d_in[21];
    const float* ln1_w = (const float*)d_in[22];
    const float* ln1_b = (const float*)d_in[23];
    const float* ffn_w1 = (const float*)d_in[24];
    const float* ffn_b1 = (const float*)d_in[25];
    const float* ffn_w2 = (const float*)d_in[26];
    const float* ffn_b2 = (const float*)d_in[27];
    const float* ln2_w = (const float*)d_in[28];
    const float* ln2_b = (const float*)d_in[29];
    const float* out_w = (const float*)d_in[30];
    const float* out_b = (const float*)d_in[31];

    // ---- workspace layout ----
    float* residual = (float*)d_ws;                  // 786,432 f
    float* dtwT  = residual + 786432;                // 221,184 f
    float* negAT = dtwT + 221184;                    // 147,456 f
    float* kvb   = negAT + 147456;                   //     768 f
    ushort_t* U = (ushort_t*)(kvb + 768);
    ushort_t* enc_bf = U;                            // 6,291,456
    ushort_t* xc   = enc_bf + 6291456;               // 1,572,864
    ushort_t* zbuf = xc + 1572864;                   // 1,572,864
    ushort_t* dblG = zbuf + 1572864;                 //   131,072
    ushort_t* yb   = dblG + 131072;                  // 1,572,864
    ushort_t* qh   = yb + 1572864;                   //   786,432
    ushort_t* ctx  = qh + 786432;                    //   786,432
    ushort_t* khv  = ctx + 786432;                   // 12,582,912
    ushort_t* ffnb = khv + 12582912;                 // 3,145,728
    ushort_t* w_in  = ffnb + 3145728;                // 7,077,888
    ushort_t* w_xp  = w_in + 7077888;                //   589,824
    ushort_t* w_out = w_xp + 589824;                 // 3,538,944
    ushort_t* w_q   = w_out + 3538944;               //   147,456
    ushort_t* w_k   = w_q + 147456;                  //   147,456
    ushort_t* w_v   = w_k + 147456;                  //   147,456 (adjacent to w_k)
    ushort_t* w_o   = w_v + 147456;                  //   147,456
    ushort_t* w_f1  = w_o + 147456;                  //   589,824
    ushort_t* w_f2  = w_f1 + 589824;                 //   589,824
    ushort_t* w_lg  = w_f2 + 589824;                 //    49,152

    const int M = B_ * T_;   // 2048
    const int MK = B_ * L_;  // 16384

    prep_kernel<<<(int)((PREP_TOTAL + 255) / 256), 256, 0, stream>>>(
        m_in_w, m_xproj_w, m_out_w, wq, wk, wv, wo, ffn_w1, ffn_w2, out_w,
        m_dt_w, m_Alog, enc, bk, bv,
        w_in, w_xp, w_out, w_q, w_k, w_v, w_o, w_f1, w_f2, w_lg,
        dtwT, negAT, enc_bf, kvb);

    init_kernel<<<(M * E_ + 255) / 256, 256, 0, stream>>>(qe, pos, residual);

    for (int l = 0; l < ND_; ++l) {
        // rmsnorm + in_proj + conv/silu -> xc, silu(z) -> zbuf
        fused_in_proj<<<dim3(M / 64, 24), 256, 0, stream>>>(
            residual, m_norm_w + (size_t)l * 384,
            w_in + (size_t)l * 1536 * 384,
            m_conv_w + (size_t)l * 768 * 4, m_conv_b + (size_t)l * 768,
            xc, zbuf);
        // xproj: xc @ Wxp^T -> dblG (bf16, cols 0..55)
        gemm_bf16<1><<<dim3(M / 64, 1), 256, 0, stream>>>(
            xc, 768, w_xp + (size_t)l * 64 * 768, nullptr, nullptr,
            dblG, M, 56, 768, 64);
        // dt-proj + scan + gate -> yb
        scan_kernel<<<dim3(12, 64), 64, 0, stream>>>(
            dblG, xc, zbuf, dtwT + (size_t)l * 24 * 768,
            m_dt_b + (size_t)l * 768, negAT + (size_t)l * 16 * 768,
            m_D + (size_t)l * 768, yb);
        // out_proj, residual += yb @ Wo^T
        gemm_bf16<0><<<dim3(M / 64, 6), 256, 0, stream>>>(
            yb, 768, w_out + (size_t)l * 384 * 768, nullptr, residual,
            residual, M, 384, 768, 384);
    }

    // final rmsnorm + q-proj
    fused_gemm<0, 0, 1><<<dim3(M / 64, 6), 256, 0, stream>>>(
        residual, rms_w, nullptr, w_q, bq, qh, 384, 384);
    // combined k|v projection (weights adjacent), N=768
    gemm_bf16<1><<<dim3(MK / 64, 12), 256, 0, stream>>>(
        enc_bf, 384, w_k, kvb, nullptr, khv, MK, 768, 384, 768);
    attn_kernel<<<B_ * H_, 256, 0, stream>>>(qh, khv, ctx);
    // o-proj, residual += ctx @ Wo^T
    gemm_bf16<0><<<dim3(M / 64, 6), 256, 0, stream>>>(
        ctx, 384, w_o, bo, residual, residual, M, 384, 384, 384);
    // ln1 + ffn1 + relu
    fused_gemm<1, 1, 1><<<dim3(M / 64, 24), 256, 0, stream>>>(
        residual, ln1_w, ln1_b, w_f1, ffn_b1, ffnb, 1536, 1536);
    // ffn2, residual +=
    gemm_bf16<0><<<dim3(M / 64, 6), 256, 0, stream>>>(
        ffnb, 1536, w_f2, ffn_b2, residual, residual, M, 384, 1536, 384);
    // ln2 + logits (fp32 out)
    fused_gemm<1, 0, 0><<<dim3(M / 64, 2), 256, 0, stream>>>(
        residual, ln2_w, ln2_b, w_lg, out_b, (float*)d_out, 97, 97);
}